// Round 5
// baseline (277.956 us; speedup 1.0000x reference)
//
#include <hip/hip_runtime.h>
#include <hip/hip_bf16.h>

#define N_NODES 10000
#define N_EDGES 320000
#define D 256

typedef __attribute__((ext_vector_type(8))) _Float16 f16x8;
typedef __attribute__((ext_vector_type(4))) _Float16 f16x4;
typedef __attribute__((ext_vector_type(4))) float f32x4;

__device__ __forceinline__ void async_copy16(const void* g, void* l) {
  __builtin_amdgcn_global_load_lds(
      (const __attribute__((address_space(1))) unsigned int*)g,
      (__attribute__((address_space(3))) unsigned int*)l, 16, 0, 0);
}

// stage W[ROWS][*] k-chunk (32 cols) into Bs[ROWS*32] with XOR quad swizzle.
// LDS dst is wave-uniform base; lane lands at base+lane*16 (HW rule). Swizzle on global side.
template<int ROWS>
__device__ __forceinline__ void stage_W(const _Float16* __restrict__ Wb, int k0, int K,
                                        _Float16* Bs, int wave, int lane) {
  const int sr = lane >> 2, ss = lane & 3;
#pragma unroll
  for (int s = 0; s < ROWS / 64; ++s) {
    int grp = wave + 4 * s;            // 16-row group
    int r = grp * 16 + sr;
    int gq = ss ^ ((r >> 1) & 3);
    async_copy16(Wb + (size_t)r * K + k0 + gq * 8, Bs + grp * 512);
  }
}
// B-frag read matching stage_W layout
__device__ __forceinline__ f16x8 read_B(const _Float16* Bs, int r, int quad) {
  return *(const f16x8*)(Bs + r * 32 + (quad ^ ((r >> 1) & 3)) * 8);
}

// ---------- prep: cast weights to fp16, pack i/g/o gate weights, edge histogram ----------
__global__ void prep_kernel(const float* __restrict__ W_rel, const float* __restrict__ W_ih,
                            const float* __restrict__ b_ih, const float* __restrict__ b_hh,
                            const float* __restrict__ W1, const float* __restrict__ W2,
                            const float* __restrict__ W3,
                            const int* __restrict__ dst, int* __restrict__ cnt,
                            _Float16* W_relh, _Float16* Wg, float* bg,
                            _Float16* W1h, _Float16* W2h, _Float16* W3h) {
  int i = blockIdx.x * 256 + threadIdx.x;
  if (i < N_EDGES) { atomicAdd(&cnt[dst[i]], 1); return; }
  i -= N_EDGES;
  if (i < 131072) { W_relh[i] = (_Float16)W_rel[i]; return; }
  i -= 131072;
  if (i < 196608) {           // W_ih rows {0-255 (i), 512-767 (g), 768-1023 (o)}
    int n = i >> 8, k = i & 255;
    int m = (n < 256) ? n : n + 256;
    Wg[i] = (_Float16)W_ih[m * 256 + k]; return;
  }
  i -= 196608;
  if (i < 32768) { W1h[i] = (_Float16)W1[i]; return; }
  i -= 32768;
  if (i < 16384) { W2h[i] = (_Float16)W2[i]; return; }
  i -= 16384;
  if (i < 32768) { W3h[i] = (_Float16)W3[i]; return; }
  i -= 32768;
  if (i < 768) { int m = (i < 256) ? i : i + 256; bg[i] = b_ih[m] + b_hh[m]; }
}

// ---------- scan ----------
__global__ __launch_bounds__(1024) void scan_kernel(const int* __restrict__ cnt,
                                                    int* __restrict__ offs,
                                                    int* __restrict__ cursors, int n) {
  __shared__ int buf[1024];
  const int t = threadIdx.x;
  int loc[10];
  int s = 0;
  int base = t * 10;
#pragma unroll
  for (int q = 0; q < 10; ++q) {
    int i = base + q;
    int v = (i < n) ? cnt[i] : 0;
    loc[q] = s;
    s += v;
  }
  buf[t] = s;
  __syncthreads();
  for (int off = 1; off < 1024; off <<= 1) {
    int x = (t >= off) ? buf[t - off] : 0;
    __syncthreads();
    buf[t] += x;
    __syncthreads();
  }
  int excl = buf[t] - s;
#pragma unroll
  for (int q = 0; q < 10; ++q) {
    int i = base + q;
    if (i < n) { int o = excl + loc[q]; offs[i] = o; cursors[i] = o; }
  }
  if (t == 1023) offs[n] = buf[1023];
}

// ---------- fill: rowoff[pos] = element offset of M row for this edge ----------
__global__ void fill_kernel(const int* __restrict__ dst, const int* __restrict__ src,
                            const int* __restrict__ rel, int* __restrict__ cursors,
                            unsigned int* __restrict__ rowoff) {
  int e = blockIdx.x * blockDim.x + threadIdx.x;
  if (e < N_EDGES) {
    int pos = atomicAdd(&cursors[dst[e]], 1);
    rowoff[pos] = (unsigned int)((rel[e] * N_NODES + src[e]) * D);
  }
}

// ---------- fused edge NN (both layers): M_r = relu(W_r relu(W_r feat + b)+ b) ----------
// grid (79, 2); block owns 128 rows x all 256 cols; H lives in LDS.
__global__ __launch_bounds__(256) void edge_fused(
    const float* __restrict__ feat, const _Float16* __restrict__ W_relh,
    const float* __restrict__ b_rel, _Float16* __restrict__ Mh)
{
  __shared__ _Float16 Hs[128 * 272];     // padded: slot = 2r+q mod 32 -> <=2-way
  __shared__ _Float16 Asb[128 * 40];     // layer-1 A staging (fp32->f16), pad 8
  __shared__ _Float16 Bsb[256 * 32];     // W staging, XOR swizzle
  const int t = threadIdx.x;
  const int wave = t >> 6, lane = t & 63;
  const int quad = lane >> 4, lrow = lane & 15;
  const int z = blockIdx.y;
  const int m0 = blockIdx.x * 128;
  const _Float16* Wb = W_relh + z * 65536;
  const float* bb = b_rel + z * 256;
  const int wm = (wave >> 1) * 64, wn = (wave & 1) * 128;

  const int arow = t >> 1, ahalf = (t & 1) * 16;
  int gr = m0 + arow; if (gr > N_NODES - 1) gr = N_NODES - 1;
  const float* fbase = feat + (size_t)gr * 256 + ahalf;

  f32x4 acc[4][8];
#pragma unroll
  for (int i = 0; i < 4; ++i)
#pragma unroll
    for (int j = 0; j < 8; ++j) acc[i][j] = (f32x4)0.0f;

  // ---- layer 1 ----
  for (int k0 = 0; k0 < 256; k0 += 32) {
    {
      const float4* fp = (const float4*)(fbase + k0);
      float4 v0 = fp[0], v1 = fp[1], v2 = fp[2], v3 = fp[3];
      f16x8 h0, h1;
      h0[0] = (_Float16)v0.x; h0[1] = (_Float16)v0.y; h0[2] = (_Float16)v0.z; h0[3] = (_Float16)v0.w;
      h0[4] = (_Float16)v1.x; h0[5] = (_Float16)v1.y; h0[6] = (_Float16)v1.z; h0[7] = (_Float16)v1.w;
      h1[0] = (_Float16)v2.x; h1[1] = (_Float16)v2.y; h1[2] = (_Float16)v2.z; h1[3] = (_Float16)v2.w;
      h1[4] = (_Float16)v3.x; h1[5] = (_Float16)v3.y; h1[6] = (_Float16)v3.z; h1[7] = (_Float16)v3.w;
      *(f16x8*)(Asb + arow * 40 + ahalf) = h0;
      *(f16x8*)(Asb + arow * 40 + ahalf + 8) = h1;
    }
    stage_W<256>(Wb, k0, 256, Bsb, wave, lane);
    __syncthreads();
    f16x8 af[4], bf[8];
#pragma unroll
    for (int i = 0; i < 4; ++i) {
      int r = wm + i * 16 + lrow;
      af[i] = *(const f16x8*)(Asb + r * 40 + quad * 8);
    }
#pragma unroll
    for (int j = 0; j < 8; ++j) bf[j] = read_B(Bsb, wn + j * 16 + lrow, quad);
#pragma unroll
    for (int i = 0; i < 4; ++i)
#pragma unroll
      for (int j = 0; j < 8; ++j)
        acc[i][j] = __builtin_amdgcn_mfma_f32_16x16x32_f16(af[i], bf[j], acc[i][j], 0, 0, 0);
    __syncthreads();
  }
  // H epilogue -> LDS (C/D layout: col=lane&15, row=quad*4+reg)
#pragma unroll
  for (int i = 0; i < 4; ++i) {
    int rb = wm + i * 16 + quad * 4;
#pragma unroll
    for (int j = 0; j < 8; ++j) {
      int col = wn + j * 16 + lrow;
      float bv = bb[col];
#pragma unroll
      for (int reg = 0; reg < 4; ++reg) {
        float c = fmaxf(acc[i][j][reg] + bv, 0.f);
        Hs[(rb + reg) * 272 + col] = (_Float16)c;
        acc[i][j][reg] = 0.f;     // reuse accumulators for layer 2
      }
    }
  }
  __syncthreads();
  // ---- layer 2 (A-frags from Hs) ----
  for (int k0 = 0; k0 < 256; k0 += 32) {
    stage_W<256>(Wb, k0, 256, Bsb, wave, lane);
    __syncthreads();
    f16x8 af[4], bf[8];
#pragma unroll
    for (int i = 0; i < 4; ++i) {
      int r = wm + i * 16 + lrow;
      af[i] = *(const f16x8*)(Hs + r * 272 + k0 + quad * 8);
    }
#pragma unroll
    for (int j = 0; j < 8; ++j) bf[j] = read_B(Bsb, wn + j * 16 + lrow, quad);
#pragma unroll
    for (int i = 0; i < 4; ++i)
#pragma unroll
      for (int j = 0; j < 8; ++j)
        acc[i][j] = __builtin_amdgcn_mfma_f32_16x16x32_f16(af[i], bf[j], acc[i][j], 0, 0, 0);
    __syncthreads();
  }
  _Float16* Mo = Mh + (size_t)z * (N_NODES * D);
#pragma unroll
  for (int i = 0; i < 4; ++i) {
    int rb = m0 + wm + i * 16 + quad * 4;
#pragma unroll
    for (int j = 0; j < 8; ++j) {
      int col = wn + j * 16 + lrow;
      float bv = bb[col];
#pragma unroll
      for (int reg = 0; reg < 4; ++reg) {
        int gm = rb + reg;
        if (gm < N_NODES) {
          float c = fmaxf(acc[i][j][reg] + bv, 0.f);
          Mo[(size_t)gm * D + col] = (_Float16)c;
        }
      }
    }
  }
}

// ---------- aggregation: one block (4 waves) per node; waves split edges; LDS reduce ----------
__global__ __launch_bounds__(256) void agg_kernel(const int* __restrict__ offs,
                                                  const unsigned int* __restrict__ rowoff,
                                                  const _Float16* __restrict__ Mh,
                                                  _Float16* __restrict__ aggh) {
  __shared__ float part[4][256];
  const int node = blockIdx.x;
  const int wave = threadIdx.x >> 6, lane = threadIdx.x & 63;
  float a0 = 0.f, a1 = 0.f, a2 = 0.f, a3 = 0.f;
  const int beg = offs[node], end = offs[node + 1];
  for (int j = beg + wave; j < end; j += 4) {
    unsigned int off = rowoff[j];
    f16x4 v = *(const f16x4*)(Mh + (size_t)off + lane * 4);
    a0 += (float)v[0]; a1 += (float)v[1]; a2 += (float)v[2]; a3 += (float)v[3];
  }
  *(float4*)&part[wave][lane * 4] = make_float4(a0, a1, a2, a3);
  __syncthreads();
  if (wave == 0) {
    float4 p0 = *(const float4*)&part[0][lane * 4];
    float4 p1 = *(const float4*)&part[1][lane * 4];
    float4 p2 = *(const float4*)&part[2][lane * 4];
    float4 p3 = *(const float4*)&part[3][lane * 4];
    f16x4 o;
    o[0] = (_Float16)(p0.x + p1.x + p2.x + p3.x);
    o[1] = (_Float16)(p0.y + p1.y + p2.y + p3.y);
    o[2] = (_Float16)(p0.z + p1.z + p2.z + p3.z);
    o[3] = (_Float16)(p0.w + p1.w + p2.w + p3.w);
    *(f16x4*)(aggh + (size_t)node * D + lane * 4) = o;
  }
}

// ---------- MFMA GEMM (used for gates): C = A(f16) @ W(f16)^T + bias ----------
template<bool RELU, bool OUTF32>
__global__ __launch_bounds__(256) void mfma_gemm(
    const _Float16* __restrict__ A, const _Float16* __restrict__ W,
    const float* __restrict__ bias, void* __restrict__ Cout,
    int M, int N, int K)
{
  __shared__ alignas(16) _Float16 As[128 * 32];
  __shared__ alignas(16) _Float16 Bs[128 * 32];
  const int t = threadIdx.x;
  const int wave = t >> 6, lane = t & 63;
  const int m0 = blockIdx.y * 128, n0 = blockIdx.x * 128;
  const int wm = (wave >> 1) * 64, wn = (wave & 1) * 64;
  const int lrow = lane & 15, quad = lane >> 4;

  f32x4 acc[4][4];
#pragma unroll
  for (int i = 0; i < 4; ++i)
#pragma unroll
    for (int j = 0; j < 4; ++j) acc[i][j] = (f32x4)0.0f;

  const int sr_loc = lane >> 2;
  const int sslot  = lane & 3;

  for (int k0 = 0; k0 < K; k0 += 32) {
#pragma unroll
    for (int s = 0; s < 2; ++s) {
      int t8 = wave + 4 * s;
      int r  = t8 * 16 + sr_loc;
      int gq = sslot ^ ((r >> 1) & 3);
      int grr = m0 + r; if (grr > M - 1) grr = M - 1;
      async_copy16(A + (size_t)grr * K + k0 + gq * 8, As + t8 * 512);
      int gn = n0 + r;
      async_copy16(W + (size_t)gn * K + k0 + gq * 8, Bs + t8 * 512);
    }
    __syncthreads();
    f16x8 af[4], bfr[4];
#pragma unroll
    for (int i = 0; i < 4; ++i) af[i] = read_B(As, wm + i * 16 + lrow, quad);
#pragma unroll
    for (int j = 0; j < 4; ++j) bfr[j] = read_B(Bs, wn + j * 16 + lrow, quad);
#pragma unroll
    for (int i = 0; i < 4; ++i)
#pragma unroll
      for (int j = 0; j < 4; ++j)
        acc[i][j] = __builtin_amdgcn_mfma_f32_16x16x32_f16(af[i], bfr[j], acc[i][j], 0, 0, 0);
    __syncthreads();
  }

#pragma unroll
  for (int i = 0; i < 4; ++i) {
    int rbase = m0 + wm + i * 16 + quad * 4;
#pragma unroll
    for (int j = 0; j < 4; ++j) {
      int col = n0 + wn + j * 16 + lrow;
      float bv = bias[col];
#pragma unroll
      for (int reg = 0; reg < 4; ++reg) {
        int gm = rbase + reg;
        if (gm < M) {
          float c = acc[i][j][reg] + bv;
          if constexpr (RELU) c = fmaxf(c, 0.f);
          if constexpr (OUTF32) ((float*)Cout)[(size_t)gm * N + col] = c;
          else ((_Float16*)Cout)[(size_t)gm * N + col] = (_Float16)c;
        }
      }
    }
  }
}

// ---------- fused LSTM + 3-layer MLP: out = W3 relu(W2 relu(W1 lstm(gates)+b1)+b2)+b3 ----------
// grid 79 blocks; block owns 128 rows; hn/x1/x2 live in LDS.
__global__ __launch_bounds__(256) void mlp_fused(
    const _Float16* __restrict__ gatesh,
    const _Float16* __restrict__ W1h, const float* __restrict__ b1,
    const _Float16* __restrict__ W2h, const float* __restrict__ b2,
    const _Float16* __restrict__ W3h, const float* __restrict__ b3,
    float* __restrict__ out)
{
  __shared__ _Float16 Hn[128 * 272];
  __shared__ _Float16 Xs[128 * 136];
  __shared__ _Float16 X2s[128 * 136];
  __shared__ _Float16 Bsb[256 * 32];
  const int t = threadIdx.x;
  const int wave = t >> 6, lane = t & 63;
  const int quad = lane >> 4, lrow = lane & 15;
  const int m0 = blockIdx.x * 128;
  const int wm = (wave >> 1) * 64;

  // ---- step a: LSTM hn from gates (i,g,o packed) ----
  {
    int row = t >> 1, dbase = (t & 1) * 128;
    int gr = m0 + row; if (gr > N_NODES - 1) gr = N_NODES - 1;
    const _Float16* g = gatesh + (size_t)gr * 768;
#pragma unroll
    for (int dd = 0; dd < 128; dd += 8) {
      int d = dbase + dd;
      f16x8 vi = *(const f16x8*)(g + d);
      f16x8 vg = *(const f16x8*)(g + 256 + d);
      f16x8 vo = *(const f16x8*)(g + 512 + d);
      f16x8 o;
#pragma unroll
      for (int e = 0; e < 8; ++e) {
        float fi = (float)vi[e], fg = (float)vg[e], fo = (float)vo[e];
        float si = 1.f / (1.f + __expf(-fi));
        float so = 1.f / (1.f + __expf(-fo));
        float c = si * tanhf(fg);
        o[e] = (_Float16)(so * tanhf(c));
      }
      *(f16x8*)(Hn + row * 272 + d) = o;
    }
  }
  __syncthreads();

  // ---- step b: x1 = relu(hn @ W1^T + b1), N=128, K=256 ----
  {
    const int wn = (wave & 1) * 64;
    f32x4 acc[4][4];
#pragma unroll
    for (int i = 0; i < 4; ++i)
#pragma unroll
      for (int j = 0; j < 4; ++j) acc[i][j] = (f32x4)0.0f;
    for (int k0 = 0; k0 < 256; k0 += 32) {
      stage_W<128>(W1h, k0, 256, Bsb, wave, lane);
      __syncthreads();
      f16x8 af[4], bf[4];
#pragma unroll
      for (int i = 0; i < 4; ++i) {
        int r = wm + i * 16 + lrow;
        af[i] = *(const f16x8*)(Hn + r * 272 + k0 + quad * 8);
      }
#pragma unroll
      for (int j = 0; j < 4; ++j) bf[j] = read_B(Bsb, wn + j * 16 + lrow, quad);
#pragma unroll
      for (int i = 0; i < 4; ++i)
#pragma unroll
        for (int j = 0; j < 4; ++j)
          acc[i][j] = __builtin_amdgcn_mfma_f32_16x16x32_f16(af[i], bf[j], acc[i][j], 0, 0, 0);
      __syncthreads();
    }
#pragma unroll
    for (int i = 0; i < 4; ++i) {
      int rb = wm + i * 16 + quad * 4;
#pragma unroll
      for (int j = 0; j < 4; ++j) {
        int col = wn + j * 16 + lrow;
        float bv = b1[col];
#pragma unroll
        for (int reg = 0; reg < 4; ++reg) {
          float c = fmaxf(acc[i][j][reg] + bv, 0.f);
          Xs[(rb + reg) * 136 + col] = (_Float16)c;
        }
      }
    }
  }
  __syncthreads();

  // ---- step c: x2 = relu(x1 @ W2^T + b2), N=128, K=128 ----
  {
    const int wn = (wave & 1) * 64;
    f32x4 acc[4][4];
#pragma unroll
    for (int i = 0; i < 4; ++i)
#pragma unroll
      for (int j = 0; j < 4; ++j) acc[i][j] = (f32x4)0.0f;
    for (int k0 = 0; k0 < 128; k0 += 32) {
      stage_W<128>(W2h, k0, 128, Bsb, wave, lane);
      __syncthreads();
      f16x8 af[4], bf[4];
#pragma unroll
      for (int i = 0; i < 4; ++i) {
        int r = wm + i * 16 + lrow;
        af[i] = *(const f16x8*)(Xs + r * 136 + k0 + quad * 8);
      }
#pragma unroll
      for (int j = 0; j < 4; ++j) bf[j] = read_B(Bsb, wn + j * 16 + lrow, quad);
#pragma unroll
      for (int i = 0; i < 4; ++i)
#pragma unroll
        for (int j = 0; j < 4; ++j)
          acc[i][j] = __builtin_amdgcn_mfma_f32_16x16x32_f16(af[i], bf[j], acc[i][j], 0, 0, 0);
      __syncthreads();
    }
#pragma unroll
    for (int i = 0; i < 4; ++i) {
      int rb = wm + i * 16 + quad * 4;
#pragma unroll
      for (int j = 0; j < 4; ++j) {
        int col = wn + j * 16 + lrow;
        float bv = b2[col];
#pragma unroll
        for (int reg = 0; reg < 4; ++reg) {
          float c = fmaxf(acc[i][j][reg] + bv, 0.f);
          X2s[(rb + reg) * 136 + col] = (_Float16)c;
        }
      }
    }
  }
  __syncthreads();

  // ---- step d: out = x2 @ W3^T + b3, N=256, K=128, fp32 out ----
  {
    const int wn = (wave & 1) * 128;
    f32x4 acc[4][8];
#pragma unroll
    for (int i = 0; i < 4; ++i)
#pragma unroll
      for (int j = 0; j < 8; ++j) acc[i][j] = (f32x4)0.0f;
    for (int k0 = 0; k0 < 128; k0 += 32) {
      stage_W<256>(W3h, k0, 128, Bsb, wave, lane);
      __syncthreads();
      f16x8 af[4], bf[8];
#pragma unroll
      for (int i = 0; i < 4; ++i) {
        int r = wm + i * 16 + lrow;
        af[i] = *(const f16x8*)(X2s + r * 136 + k0 + quad * 8);
      }
#pragma unroll
      for (int j = 0; j < 8; ++j) bf[j] = read_B(Bsb, wn + j * 16 + lrow, quad);
#pragma unroll
      for (int i = 0; i < 4; ++i)
#pragma unroll
        for (int j = 0; j < 8; ++j)
          acc[i][j] = __builtin_amdgcn_mfma_f32_16x16x32_f16(af[i], bf[j], acc[i][j], 0, 0, 0);
      __syncthreads();
    }
#pragma unroll
    for (int i = 0; i < 4; ++i) {
      int rb = m0 + wm + i * 16 + quad * 4;
#pragma unroll
      for (int j = 0; j < 8; ++j) {
        int col = wn + j * 16 + lrow;
        float bv = b3[col];
#pragma unroll
        for (int reg = 0; reg < 4; ++reg) {
          int gm = rb + reg;
          if (gm < N_NODES) out[(size_t)gm * 256 + col] = acc[i][j][reg] + bv;
        }
      }
    }
  }
}

// ---------- launch ----------
extern "C" void kernel_launch(void* const* d_in, const int* in_sizes, int n_in,
                              void* d_out, int out_size, void* d_ws, size_t ws_size,
                              hipStream_t stream) {
  const float* feat  = (const float*)d_in[0];
  const int* src = (const int*)d_in[1];
  const int* dst = (const int*)d_in[2];
  const int* rel = (const int*)d_in[3];
  const float* W_rel = (const float*)d_in[4];
  const float* b_rel = (const float*)d_in[5];
  const float* W_ih  = (const float*)d_in[6];
  const float* b_ih  = (const float*)d_in[7];
  const float* b_hh  = (const float*)d_in[8];
  const float* W1 = (const float*)d_in[9];
  const float* b1 = (const float*)d_in[10];
  const float* W2 = (const float*)d_in[11];
  const float* b2 = (const float*)d_in[12];
  const float* W3 = (const float*)d_in[13];
  const float* b3 = (const float*)d_in[14];
  float* out = (float*)d_out;

  char* ws = (char*)d_ws;
  _Float16* Mh     = (_Float16*)(ws);              // 10,240,000 B (2 rel slabs)
  _Float16* aggh   = (_Float16*)(ws + 10240000);   //  5,120,000
  _Float16* gatesh = (_Float16*)(ws + 15360000);   // 15,360,000
  char* wsb = ws + 30720000;
  _Float16* W_relh = (_Float16*)(wsb);             // 262,144
  _Float16* Wg     = (_Float16*)(wsb + 262144);    // 393,216
  _Float16* W1h    = (_Float16*)(wsb + 655360);    // 65,536
  _Float16* W2h    = (_Float16*)(wsb + 720896);    // 32,768
  _Float16* W3h    = (_Float16*)(wsb + 753664);    // 65,536
  float*    bg     = (float*)(wsb + 819200);       // 3,072
  int*      cnt    = (int*)(wsb + 822272);         // 40,000
  int*      offs   = (int*)(wsb + 862272);         // 40,004 (+pad)
  int*      cursors= (int*)(wsb + 902280);         // 40,000
  unsigned int* rowoff = (unsigned int*)(wsb + 942280);  // 1,280,000

  (void)hipMemsetAsync(cnt, 0, N_NODES * sizeof(int), stream);
  // prep: hist(320000) + W_rel(131072) + Wg(196608) + W1(32768) + W2(16384) + W3(32768) + bg(768)
  prep_kernel<<<2853, 256, 0, stream>>>(W_rel, W_ih, b_ih, b_hh, W1, W2, W3,
                                        dst, cnt, W_relh, Wg, bg, W1h, W2h, W3h);
  scan_kernel<<<1, 1024, 0, stream>>>(cnt, offs, cursors, N_NODES);
  fill_kernel<<<1250, 256, 0, stream>>>(dst, src, rel, cursors, rowoff);

  const int MB = (N_NODES + 127) / 128;  // 79

  // fused edge NN (both layers, both relations)
  edge_fused<<<dim3(MB, 2), 256, 0, stream>>>(feat, W_relh, b_rel, Mh);

  // scatter-sum via sorted gather
  agg_kernel<<<N_NODES, 256, 0, stream>>>(offs, rowoff, Mh, aggh);

  // gates (i,g,o) = agg @ Wg^T + bg
  mfma_gemm<false, false><<<dim3(6, MB), 256, 0, stream>>>(
      aggh, Wg, bg, gatesh, N_NODES, 768, 256);

  // fused LSTM + MLP -> out
  mlp_fused<<<MB, 256, 0, stream>>>(gatesh, W1h, b1, W2h, b2, W3h, b3, out);
}

// Round 6
// 264.201 us; speedup vs baseline: 1.0521x; 1.0521x over previous
//
#include <hip/hip_runtime.h>
#include <hip/hip_bf16.h>

#define N_NODES 10000
#define N_EDGES 320000
#define D 256

typedef __attribute__((ext_vector_type(8))) _Float16 f16x8;
typedef __attribute__((ext_vector_type(4))) _Float16 f16x4;
typedef __attribute__((ext_vector_type(4))) float f32x4;

__device__ __forceinline__ void async_copy16(const void* g, void* l) {
  __builtin_amdgcn_global_load_lds(
      (const __attribute__((address_space(1))) unsigned int*)g,
      (__attribute__((address_space(3))) unsigned int*)l, 16, 0, 0);
}

// stage W[ROWS][*] k-chunk (32 cols) into Bs[ROWS*32] with XOR quad swizzle (for gates GEMM)
template<int ROWS>
__device__ __forceinline__ void stage_W(const _Float16* __restrict__ Wb, int k0, int K,
                                        _Float16* Bs, int wave, int lane) {
  const int sr = lane >> 2, ss = lane & 3;
#pragma unroll
  for (int s = 0; s < ROWS / 64; ++s) {
    int grp = wave + 4 * s;
    int r = grp * 16 + sr;
    int gq = ss ^ ((r >> 1) & 3);
    async_copy16(Wb + (size_t)r * K + k0 + gq * 8, Bs + grp * 512);
  }
}
__device__ __forceinline__ f16x8 read_B(const _Float16* Bs, int r, int quad) {
  return *(const f16x8*)(Bs + r * 32 + (quad ^ ((r >> 1) & 3)) * 8);
}

__device__ __forceinline__ float fast_sigmoid(float x) {
  return __builtin_amdgcn_rcpf(1.f + __expf(-x));
}
__device__ __forceinline__ float fast_tanh(float x) {
  float ax = fabsf(x);
  float e = __expf(-2.f * ax);
  float t = (1.f - e) * __builtin_amdgcn_rcpf(1.f + e);
  return copysignf(t, x);
}

// ---------- prep: cast weights to fp16, pack i/g/o gate weights, edge histogram ----------
__global__ void prep_kernel(const float* __restrict__ W_rel, const float* __restrict__ W_ih,
                            const float* __restrict__ b_ih, const float* __restrict__ b_hh,
                            const float* __restrict__ W1, const float* __restrict__ W2,
                            const float* __restrict__ W3,
                            const int* __restrict__ dst, int* __restrict__ cnt,
                            _Float16* W_relh, _Float16* Wg, float* bg,
                            _Float16* W1h, _Float16* W2h, _Float16* W3h) {
  int i = blockIdx.x * 256 + threadIdx.x;
  if (i < N_EDGES) { atomicAdd(&cnt[dst[i]], 1); return; }
  i -= N_EDGES;
  if (i < 131072) { W_relh[i] = (_Float16)W_rel[i]; return; }
  i -= 131072;
  if (i < 196608) {           // W_ih rows {0-255 (i), 512-767 (g), 768-1023 (o)}
    int n = i >> 8, k = i & 255;
    int m = (n < 256) ? n : n + 256;
    Wg[i] = (_Float16)W_ih[m * 256 + k]; return;
  }
  i -= 196608;
  if (i < 32768) { W1h[i] = (_Float16)W1[i]; return; }
  i -= 32768;
  if (i < 16384) { W2h[i] = (_Float16)W2[i]; return; }
  i -= 16384;
  if (i < 32768) { W3h[i] = (_Float16)W3[i]; return; }
  i -= 32768;
  if (i < 768) { int m = (i < 256) ? i : i + 256; bg[i] = b_ih[m] + b_hh[m]; }
}

// ---------- scan ----------
__global__ __launch_bounds__(1024) void scan_kernel(const int* __restrict__ cnt,
                                                    int* __restrict__ offs,
                                                    int* __restrict__ cursors, int n) {
  __shared__ int buf[1024];
  const int t = threadIdx.x;
  int loc[10];
  int s = 0;
  int base = t * 10;
#pragma unroll
  for (int q = 0; q < 10; ++q) {
    int i = base + q;
    int v = (i < n) ? cnt[i] : 0;
    loc[q] = s;
    s += v;
  }
  buf[t] = s;
  __syncthreads();
  for (int off = 1; off < 1024; off <<= 1) {
    int x = (t >= off) ? buf[t - off] : 0;
    __syncthreads();
    buf[t] += x;
    __syncthreads();
  }
  int excl = buf[t] - s;
#pragma unroll
  for (int q = 0; q < 10; ++q) {
    int i = base + q;
    if (i < n) { int o = excl + loc[q]; offs[i] = o; cursors[i] = o; }
  }
  if (t == 1023) offs[n] = buf[1023];
}

// ---------- fill ----------
__global__ void fill_kernel(const int* __restrict__ dst, const int* __restrict__ src,
                            const int* __restrict__ rel, int* __restrict__ cursors,
                            unsigned int* __restrict__ rowoff) {
  int e = blockIdx.x * blockDim.x + threadIdx.x;
  if (e < N_EDGES) {
    int pos = atomicAdd(&cursors[dst[e]], 1);
    rowoff[pos] = (unsigned int)((rel[e] * N_NODES + src[e]) * D);
  }
}

// ---------- fused edge NN, wave-parallel: M_r = relu(W_r relu(W_r feat + b) + b) ----------
// grid (157, 2); 64-row blocks; 4 waves each own 32 rows x 128 cols; B-frags from global L2.
__global__ __launch_bounds__(256) void edge_fused(
    const float* __restrict__ feat, const _Float16* __restrict__ W_relh,
    const float* __restrict__ b_rel, _Float16* __restrict__ Mh)
{
  __shared__ _Float16 As[64 * 264];
  __shared__ _Float16 Hs[64 * 264];
  const int t = threadIdx.x;
  const int wave = t >> 6, lane = t & 63;
  const int quad = lane >> 4, lrow = lane & 15;
  const int z = blockIdx.y;
  const int m0 = blockIdx.x * 64;
  const _Float16* Wb = W_relh + z * 65536;
  const float* bb = b_rel + z * 256;
  const int wm = (wave >> 1) * 32;      // 0 or 32
  const int wn = (wave & 1) * 128;      // 0 or 128

  // ---- stage A: 64 rows x 256 cols, fp32 -> f16, once for all K ----
  {
    int row = t >> 2;
    int c0 = (t & 3) * 64;
    int gr = m0 + row; if (gr > N_NODES - 1) gr = N_NODES - 1;
    const float* fb = feat + (size_t)gr * 256 + c0;
#pragma unroll
    for (int u = 0; u < 8; ++u) {
      float4 v0 = *(const float4*)(fb + u * 8);
      float4 v1 = *(const float4*)(fb + u * 8 + 4);
      f16x8 h;
      h[0] = (_Float16)v0.x; h[1] = (_Float16)v0.y; h[2] = (_Float16)v0.z; h[3] = (_Float16)v0.w;
      h[4] = (_Float16)v1.x; h[5] = (_Float16)v1.y; h[6] = (_Float16)v1.z; h[7] = (_Float16)v1.w;
      *(f16x8*)(As + row * 264 + c0 + u * 8) = h;
    }
  }
  __syncthreads();

  f32x4 acc[2][8];
#pragma unroll
  for (int i = 0; i < 2; ++i)
#pragma unroll
    for (int j = 0; j < 8; ++j) acc[i][j] = (f32x4)0.0f;

  // ---- layer 1: A from As (LDS), B from global (L2-resident W) ----
#pragma unroll
  for (int kc = 0; kc < 8; ++kc) {
    f16x8 af0 = *(const f16x8*)(As + (wm + lrow) * 264 + kc * 32 + quad * 8);
    f16x8 af1 = *(const f16x8*)(As + (wm + 16 + lrow) * 264 + kc * 32 + quad * 8);
#pragma unroll
    for (int j = 0; j < 8; ++j) {
      f16x8 bf = *(const f16x8*)(Wb + (size_t)(wn + j * 16 + lrow) * 256 + kc * 32 + quad * 8);
      acc[0][j] = __builtin_amdgcn_mfma_f32_16x16x32_f16(af0, bf, acc[0][j], 0, 0, 0);
      acc[1][j] = __builtin_amdgcn_mfma_f32_16x16x32_f16(af1, bf, acc[1][j], 0, 0, 0);
    }
  }
  // H epilogue -> Hs (C/D layout: col=lane&15, row=quad*4+reg)
#pragma unroll
  for (int i = 0; i < 2; ++i) {
    int rb = wm + i * 16 + quad * 4;
#pragma unroll
    for (int j = 0; j < 8; ++j) {
      int col = wn + j * 16 + lrow;
      float bv = bb[col];
#pragma unroll
      for (int reg = 0; reg < 4; ++reg) {
        float c = fmaxf(acc[i][j][reg] + bv, 0.f);
        Hs[(rb + reg) * 264 + col] = (_Float16)c;
        acc[i][j][reg] = 0.f;
      }
    }
  }
  __syncthreads();

  // ---- layer 2 (tied W): A from Hs ----
#pragma unroll
  for (int kc = 0; kc < 8; ++kc) {
    f16x8 af0 = *(const f16x8*)(Hs + (wm + lrow) * 264 + kc * 32 + quad * 8);
    f16x8 af1 = *(const f16x8*)(Hs + (wm + 16 + lrow) * 264 + kc * 32 + quad * 8);
#pragma unroll
    for (int j = 0; j < 8; ++j) {
      f16x8 bf = *(const f16x8*)(Wb + (size_t)(wn + j * 16 + lrow) * 256 + kc * 32 + quad * 8);
      acc[0][j] = __builtin_amdgcn_mfma_f32_16x16x32_f16(af0, bf, acc[0][j], 0, 0, 0);
      acc[1][j] = __builtin_amdgcn_mfma_f32_16x16x32_f16(af1, bf, acc[1][j], 0, 0, 0);
    }
  }
  // M epilogue -> global
  _Float16* Mo = Mh + (size_t)z * (N_NODES * D);
#pragma unroll
  for (int i = 0; i < 2; ++i) {
    int rb = m0 + wm + i * 16 + quad * 4;
#pragma unroll
    for (int j = 0; j < 8; ++j) {
      int col = wn + j * 16 + lrow;
      float bv = bb[col];
#pragma unroll
      for (int reg = 0; reg < 4; ++reg) {
        int gm = rb + reg;
        if (gm < N_NODES) {
          float c = fmaxf(acc[i][j][reg] + bv, 0.f);
          Mo[(size_t)gm * D + col] = (_Float16)c;
        }
      }
    }
  }
}

// ---------- aggregation: one block (4 waves) per node; waves split edges; LDS reduce ----------
__global__ __launch_bounds__(256) void agg_kernel(const int* __restrict__ offs,
                                                  const unsigned int* __restrict__ rowoff,
                                                  const _Float16* __restrict__ Mh,
                                                  _Float16* __restrict__ aggh) {
  __shared__ float part[4][256];
  const int node = blockIdx.x;
  const int wave = threadIdx.x >> 6, lane = threadIdx.x & 63;
  float a0 = 0.f, a1 = 0.f, a2 = 0.f, a3 = 0.f;
  const int beg = offs[node], end = offs[node + 1];
  for (int j = beg + wave; j < end; j += 4) {
    unsigned int off = rowoff[j];
    f16x4 v = *(const f16x4*)(Mh + (size_t)off + lane * 4);
    a0 += (float)v[0]; a1 += (float)v[1]; a2 += (float)v[2]; a3 += (float)v[3];
  }
  *(float4*)&part[wave][lane * 4] = make_float4(a0, a1, a2, a3);
  __syncthreads();
  if (wave == 0) {
    float4 p0 = *(const float4*)&part[0][lane * 4];
    float4 p1 = *(const float4*)&part[1][lane * 4];
    float4 p2 = *(const float4*)&part[2][lane * 4];
    float4 p3 = *(const float4*)&part[3][lane * 4];
    f16x4 o;
    o[0] = (_Float16)(p0.x + p1.x + p2.x + p3.x);
    o[1] = (_Float16)(p0.y + p1.y + p2.y + p3.y);
    o[2] = (_Float16)(p0.z + p1.z + p2.z + p3.z);
    o[3] = (_Float16)(p0.w + p1.w + p2.w + p3.w);
    *(f16x4*)(aggh + (size_t)node * D + lane * 4) = o;
  }
}

// ---------- MFMA GEMM (gates): C = A(f16) @ W(f16)^T + bias, f16 out ----------
__global__ __launch_bounds__(256) void mfma_gemm(
    const _Float16* __restrict__ A, const _Float16* __restrict__ W,
    const float* __restrict__ bias, _Float16* __restrict__ Cout,
    int M, int N, int K)
{
  __shared__ alignas(16) _Float16 As[128 * 32];
  __shared__ alignas(16) _Float16 Bs[128 * 32];
  const int t = threadIdx.x;
  const int wave = t >> 6, lane = t & 63;
  const int m0 = blockIdx.y * 128, n0 = blockIdx.x * 128;
  const int wm = (wave >> 1) * 64, wn = (wave & 1) * 64;
  const int lrow = lane & 15, quad = lane >> 4;

  f32x4 acc[4][4];
#pragma unroll
  for (int i = 0; i < 4; ++i)
#pragma unroll
    for (int j = 0; j < 4; ++j) acc[i][j] = (f32x4)0.0f;

  const int sr_loc = lane >> 2;
  const int sslot  = lane & 3;

  for (int k0 = 0; k0 < K; k0 += 32) {
#pragma unroll
    for (int s = 0; s < 2; ++s) {
      int t8 = wave + 4 * s;
      int r  = t8 * 16 + sr_loc;
      int gq = sslot ^ ((r >> 1) & 3);
      int grr = m0 + r; if (grr > M - 1) grr = M - 1;
      async_copy16(A + (size_t)grr * K + k0 + gq * 8, As + t8 * 512);
      int gn = n0 + r;
      async_copy16(W + (size_t)gn * K + k0 + gq * 8, Bs + t8 * 512);
    }
    __syncthreads();
    f16x8 af[4], bfr[4];
#pragma unroll
    for (int i = 0; i < 4; ++i) af[i] = read_B(As, wm + i * 16 + lrow, quad);
#pragma unroll
    for (int j = 0; j < 4; ++j) bfr[j] = read_B(Bs, wn + j * 16 + lrow, quad);
#pragma unroll
    for (int i = 0; i < 4; ++i)
#pragma unroll
      for (int j = 0; j < 4; ++j)
        acc[i][j] = __builtin_amdgcn_mfma_f32_16x16x32_f16(af[i], bfr[j], acc[i][j], 0, 0, 0);
    __syncthreads();
  }

#pragma unroll
  for (int i = 0; i < 4; ++i) {
    int rbase = m0 + wm + i * 16 + quad * 4;
#pragma unroll
    for (int j = 0; j < 4; ++j) {
      int col = n0 + wn + j * 16 + lrow;
      float bv = bias[col];
#pragma unroll
      for (int reg = 0; reg < 4; ++reg) {
        int gm = rbase + reg;
        if (gm < M) Cout[(size_t)gm * N + col] = (_Float16)(acc[i][j][reg] + bv);
      }
    }
  }
}

// ---------- fused LSTM + MLP, one wave per 16 rows, zero inter-wave deps ----------
// grid 625 x 64 threads; B-fragments straight from global (weights are L2-resident).
__global__ __launch_bounds__(64) void mlp_fused(
    const _Float16* __restrict__ gatesh,
    const _Float16* __restrict__ W1h, const float* __restrict__ b1,
    const _Float16* __restrict__ W2h, const float* __restrict__ b2,
    const _Float16* __restrict__ W3h, const float* __restrict__ b3,
    float* __restrict__ out)
{
  __shared__ _Float16 Hn[16 * 264];
  __shared__ _Float16 Xs[16 * 136];
  __shared__ _Float16 X2s[16 * 136];
  const int lane = threadIdx.x;
  const int quad = lane >> 4, lrow = lane & 15;
  const int r0 = blockIdx.x * 16;   // 625*16 == 10000 exactly

  // ---- LSTM: hn = sigm(o)*tanh(sigm(i)*tanh(g)) ----
#pragma unroll 4
  for (int row = 0; row < 16; ++row) {
    const _Float16* g = gatesh + (size_t)(r0 + row) * 768 + lane * 4;
    f16x4 vi = *(const f16x4*)(g);
    f16x4 vg = *(const f16x4*)(g + 256);
    f16x4 vo = *(const f16x4*)(g + 512);
    f16x4 o;
#pragma unroll
    for (int e = 0; e < 4; ++e) {
      float c = fast_sigmoid((float)vi[e]) * fast_tanh((float)vg[e]);
      o[e] = (_Float16)(fast_sigmoid((float)vo[e]) * fast_tanh(c));
    }
    *(f16x4*)(Hn + row * 264 + lane * 4) = o;
  }
  __syncthreads();

  // ---- x1 = relu(hn @ W1^T + b1): N=128, K=256 ----
  {
    f16x8 af[8];
#pragma unroll
    for (int kc = 0; kc < 8; ++kc)
      af[kc] = *(const f16x8*)(Hn + lrow * 264 + kc * 32 + quad * 8);
    f32x4 acc[8];
#pragma unroll
    for (int j = 0; j < 8; ++j) acc[j] = (f32x4)0.0f;
#pragma unroll
    for (int kc = 0; kc < 8; ++kc)
#pragma unroll
      for (int j = 0; j < 8; ++j) {
        f16x8 bf = *(const f16x8*)(W1h + (size_t)(j * 16 + lrow) * 256 + kc * 32 + quad * 8);
        acc[j] = __builtin_amdgcn_mfma_f32_16x16x32_f16(af[kc], bf, acc[j], 0, 0, 0);
      }
#pragma unroll
    for (int j = 0; j < 8; ++j) {
      int col = j * 16 + lrow;
      float bv = b1[col];
#pragma unroll
      for (int reg = 0; reg < 4; ++reg)
        Xs[(quad * 4 + reg) * 136 + col] = (_Float16)fmaxf(acc[j][reg] + bv, 0.f);
    }
  }
  __syncthreads();

  // ---- x2 = relu(x1 @ W2^T + b2): N=128, K=128 ----
  {
    f16x8 af[4];
#pragma unroll
    for (int kc = 0; kc < 4; ++kc)
      af[kc] = *(const f16x8*)(Xs + lrow * 136 + kc * 32 + quad * 8);
    f32x4 acc[8];
#pragma unroll
    for (int j = 0; j < 8; ++j) acc[j] = (f32x4)0.0f;
#pragma unroll
    for (int kc = 0; kc < 4; ++kc)
#pragma unroll
      for (int j = 0; j < 8; ++j) {
        f16x8 bf = *(const f16x8*)(W2h + (size_t)(j * 16 + lrow) * 128 + kc * 32 + quad * 8);
        acc[j] = __builtin_amdgcn_mfma_f32_16x16x32_f16(af[kc], bf, acc[j], 0, 0, 0);
      }
#pragma unroll
    for (int j = 0; j < 8; ++j) {
      int col = j * 16 + lrow;
      float bv = b2[col];
#pragma unroll
      for (int reg = 0; reg < 4; ++reg)
        X2s[(quad * 4 + reg) * 136 + col] = (_Float16)fmaxf(acc[j][reg] + bv, 0.f);
    }
  }
  __syncthreads();

  // ---- out = x2 @ W3^T + b3: N=256, K=128, fp32 out ----
  {
    f16x8 af[4];
#pragma unroll
    for (int kc = 0; kc < 4; ++kc)
      af[kc] = *(const f16x8*)(X2s + lrow * 136 + kc * 32 + quad * 8);
    f32x4 acc[16];
#pragma unroll
    for (int j = 0; j < 16; ++j) acc[j] = (f32x4)0.0f;
#pragma unroll
    for (int kc = 0; kc < 4; ++kc)
#pragma unroll
      for (int j = 0; j < 16; ++j) {
        f16x8 bf = *(const f16x8*)(W3h + (size_t)(j * 16 + lrow) * 128 + kc * 32 + quad * 8);
        acc[j] = __builtin_amdgcn_mfma_f32_16x16x32_f16(af[kc], bf, acc[j], 0, 0, 0);
      }
#pragma unroll
    for (int j = 0; j < 16; ++j) {
      int col = j * 16 + lrow;
      float bv = b3[col];
#pragma unroll
      for (int reg = 0; reg < 4; ++reg)
        out[(size_t)(r0 + quad * 4 + reg) * 256 + col] = acc[j][reg] + bv;
    }
  }
}

// ---------- launch ----------
extern "C" void kernel_launch(void* const* d_in, const int* in_sizes, int n_in,
                              void* d_out, int out_size, void* d_ws, size_t ws_size,
                              hipStream_t stream) {
  const float* feat  = (const float*)d_in[0];
  const int* src = (const int*)d_in[1];
  const int* dst = (const int*)d_in[2];
  const int* rel = (const int*)d_in[3];
  const float* W_rel = (const float*)d_in[4];
  const float* b_rel = (const float*)d_in[5];
  const float* W_ih  = (const float*)d_in[6];
  const float* b_ih  = (const float*)d_in[7];
  const float* b_hh  = (const float*)d_in[8];
  const float* W1 = (const float*)d_in[9];
  const float* b1 = (const float*)d_in[10];
  const float* W2 = (const float*)d_in[11];
  const float* b2 = (const float*)d_in[12];
  const float* W3 = (const float*)d_in[13];
  const float* b3 = (const float*)d_in[14];
  float* out = (float*)d_out;

  char* ws = (char*)d_ws;
  _Float16* Mh     = (_Float16*)(ws);              // 10,240,000 B (2 rel slabs)
  _Float16* aggh   = (_Float16*)(ws + 10240000);   //  5,120,000
  _Float16* gatesh = (_Float16*)(ws + 15360000);   // 15,360,000
  char* wsb = ws + 30720000;
  _Float16* W_relh = (_Float16*)(wsb);             // 262,144
  _Float16* Wg     = (_Float16*)(wsb + 262144);    // 393,216
  _Float16* W1h    = (_Float16*)(wsb + 655360);    // 65,536
  _Float16* W2h    = (_Float16*)(wsb + 720896);    // 32,768
  _Float16* W3h    = (_Float16*)(wsb + 753664);    // 65,536
  float*    bg     = (float*)(wsb + 819200);       // 3,072
  int*      cnt    = (int*)(wsb + 822272);         // 40,000
  int*      offs   = (int*)(wsb + 862272);         // 40,004 (+pad)
  int*      cursors= (int*)(wsb + 902280);         // 40,000
  unsigned int* rowoff = (unsigned int*)(wsb + 942280);  // 1,280,000

  (void)hipMemsetAsync(cnt, 0, N_NODES * sizeof(int), stream);
  prep_kernel<<<2853, 256, 0, stream>>>(W_rel, W_ih, b_ih, b_hh, W1, W2, W3,
                                        dst, cnt, W_relh, Wg, bg, W1h, W2h, W3h);
  scan_kernel<<<1, 1024, 0, stream>>>(cnt, offs, cursors, N_NODES);
  fill_kernel<<<1250, 256, 0, stream>>>(dst, src, rel, cursors, rowoff);

  // fused edge NN (both layers, both relations), wave-parallel
  edge_fused<<<dim3(157, 2), 256, 0, stream>>>(feat, W_relh, b_rel, Mh);

  // scatter-sum via sorted gather
  agg_kernel<<<N_NODES, 256, 0, stream>>>(offs, rowoff, Mh, aggh);

  // gates (i,g,o) = agg @ Wg^T + bg
  mfma_gemm<<<dim3(6, 79), 256, 0, stream>>>(aggh, Wg, bg, gatesh, N_NODES, 768, 256);

  // fused LSTM + MLP -> out, wave-parallel
  mlp_fused<<<625, 64, 0, stream>>>(gatesh, W1h, b1, W2h, b2, W3h, b3, out);
}

// Round 7
// 251.823 us; speedup vs baseline: 1.1038x; 1.0492x over previous
//
#include <hip/hip_runtime.h>
#include <hip/hip_bf16.h>

#define N_NODES 10000
#define N_EDGES 320000
#define D 256

typedef __attribute__((ext_vector_type(8))) _Float16 f16x8;
typedef __attribute__((ext_vector_type(4))) _Float16 f16x4;
typedef __attribute__((ext_vector_type(4))) float f32x4;

__device__ __forceinline__ void async_copy16(const void* g, void* l) {
  __builtin_amdgcn_global_load_lds(
      (const __attribute__((address_space(1))) unsigned int*)g,
      (__attribute__((address_space(3))) unsigned int*)l, 16, 0, 0);
}

// stage W[ROWS][*] k-chunk (32 cols) into Bs[ROWS*32] with XOR quad swizzle
template<int ROWS>
__device__ __forceinline__ void stage_W(const _Float16* __restrict__ Wb, int k0, int K,
                                        _Float16* Bs, int wave, int lane) {
  const int sr = lane >> 2, ss = lane & 3;
#pragma unroll
  for (int s = 0; s < ROWS / 64; ++s) {
    int grp = wave + 4 * s;
    int r = grp * 16 + sr;
    int gq = ss ^ ((r >> 1) & 3);
    async_copy16(Wb + (size_t)r * K + k0 + gq * 8, Bs + grp * 512);
  }
}
__device__ __forceinline__ f16x8 read_B(const _Float16* Bs, int r, int quad) {
  return *(const f16x8*)(Bs + r * 32 + (quad ^ ((r >> 1) & 3)) * 8);
}

__device__ __forceinline__ float fast_sigmoid(float x) {
  return __builtin_amdgcn_rcpf(1.f + __expf(-x));
}
__device__ __forceinline__ float fast_tanh(float x) {
  float ax = fabsf(x);
  float e = __expf(-2.f * ax);
  float t = (1.f - e) * __builtin_amdgcn_rcpf(1.f + e);
  return copysignf(t, x);
}

// ---------- prep: cast weights to fp16, pack i/g/o gate weights, edge histogram ----------
__global__ void prep_kernel(const float* __restrict__ W_rel, const float* __restrict__ W_ih,
                            const float* __restrict__ b_ih, const float* __restrict__ b_hh,
                            const float* __restrict__ W1, const float* __restrict__ W2,
                            const float* __restrict__ W3,
                            const int* __restrict__ dst, int* __restrict__ cnt,
                            _Float16* W_relh, _Float16* Wg, float* bg,
                            _Float16* W1h, _Float16* W2h, _Float16* W3h) {
  int i = blockIdx.x * 256 + threadIdx.x;
  if (i < N_EDGES) { atomicAdd(&cnt[dst[i]], 1); return; }
  i -= N_EDGES;
  if (i < 131072) { W_relh[i] = (_Float16)W_rel[i]; return; }
  i -= 131072;
  if (i < 196608) {           // W_ih rows {0-255 (i), 512-767 (g), 768-1023 (o)}
    int n = i >> 8, k = i & 255;
    int m = (n < 256) ? n : n + 256;
    Wg[i] = (_Float16)W_ih[m * 256 + k]; return;
  }
  i -= 196608;
  if (i < 32768) { W1h[i] = (_Float16)W1[i]; return; }
  i -= 32768;
  if (i < 16384) { W2h[i] = (_Float16)W2[i]; return; }
  i -= 16384;
  if (i < 32768) { W3h[i] = (_Float16)W3[i]; return; }
  i -= 32768;
  if (i < 768) { int m = (i < 256) ? i : i + 256; bg[i] = b_ih[m] + b_hh[m]; }
}

// ---------- scan ----------
__global__ __launch_bounds__(1024) void scan_kernel(const int* __restrict__ cnt,
                                                    int* __restrict__ offs,
                                                    int* __restrict__ cursors, int n) {
  __shared__ int buf[1024];
  const int t = threadIdx.x;
  int loc[10];
  int s = 0;
  int base = t * 10;
#pragma unroll
  for (int q = 0; q < 10; ++q) {
    int i = base + q;
    int v = (i < n) ? cnt[i] : 0;
    loc[q] = s;
    s += v;
  }
  buf[t] = s;
  __syncthreads();
  for (int off = 1; off < 1024; off <<= 1) {
    int x = (t >= off) ? buf[t - off] : 0;
    __syncthreads();
    buf[t] += x;
    __syncthreads();
  }
  int excl = buf[t] - s;
#pragma unroll
  for (int q = 0; q < 10; ++q) {
    int i = base + q;
    if (i < n) { int o = excl + loc[q]; offs[i] = o; cursors[i] = o; }
  }
  if (t == 1023) offs[n] = buf[1023];
}

// ---------- fill ----------
__global__ void fill_kernel(const int* __restrict__ dst, const int* __restrict__ src,
                            const int* __restrict__ rel, int* __restrict__ cursors,
                            unsigned int* __restrict__ rowoff) {
  int e = blockIdx.x * blockDim.x + threadIdx.x;
  if (e < N_EDGES) {
    int pos = atomicAdd(&cursors[dst[e]], 1);
    rowoff[pos] = (unsigned int)((rel[e] * N_NODES + src[e]) * D);
  }
}

// ---------- fused edge NN v2: LDS-staged B, global-cvt A (layer 1), Hs in LDS ----------
// grid (157, 2); block = 64 rows x 256 cols; 4 waves: wm in {0,32}, wn in {0,128}.
__global__ __launch_bounds__(256) void edge_fused(
    const float* __restrict__ feat, const _Float16* __restrict__ W_relh,
    const float* __restrict__ b_rel, _Float16* __restrict__ Mh)
{
  __shared__ _Float16 Hs[64 * 264];        // 33,792 B
  __shared__ alignas(16) _Float16 Bs[256 * 32];  // 16,384 B
  const int t = threadIdx.x;
  const int wave = t >> 6, lane = t & 63;
  const int quad = lane >> 4, lrow = lane & 15;
  const int z = blockIdx.y;
  const int m0 = blockIdx.x * 64;
  const _Float16* Wb = W_relh + z * 65536;
  const float* bb = b_rel + z * 256;
  const int wm = (wave >> 1) * 32;
  const int wn = (wave & 1) * 128;

  int ar0 = m0 + wm + lrow;      if (ar0 > N_NODES - 1) ar0 = N_NODES - 1;
  int ar1 = m0 + wm + 16 + lrow; if (ar1 > N_NODES - 1) ar1 = N_NODES - 1;
  const float* fr0 = feat + (size_t)ar0 * 256;
  const float* fr1 = feat + (size_t)ar1 * 256;

  f32x4 acc[2][8];
#pragma unroll
  for (int i = 0; i < 2; ++i)
#pragma unroll
    for (int j = 0; j < 8; ++j) acc[i][j] = (f32x4)0.0f;

  // ---- layer 1: A from global fp32 (cvt), B from LDS ----
#pragma unroll
  for (int kc = 0; kc < 8; ++kc) {
    stage_W<256>(Wb, kc * 32, 256, Bs, wave, lane);
    float4 u0 = *(const float4*)(fr0 + kc * 32 + quad * 8);
    float4 u1 = *(const float4*)(fr0 + kc * 32 + quad * 8 + 4);
    float4 v0 = *(const float4*)(fr1 + kc * 32 + quad * 8);
    float4 v1 = *(const float4*)(fr1 + kc * 32 + quad * 8 + 4);
    f16x8 af0, af1;
    af0[0] = (_Float16)u0.x; af0[1] = (_Float16)u0.y; af0[2] = (_Float16)u0.z; af0[3] = (_Float16)u0.w;
    af0[4] = (_Float16)u1.x; af0[5] = (_Float16)u1.y; af0[6] = (_Float16)u1.z; af0[7] = (_Float16)u1.w;
    af1[0] = (_Float16)v0.x; af1[1] = (_Float16)v0.y; af1[2] = (_Float16)v0.z; af1[3] = (_Float16)v0.w;
    af1[4] = (_Float16)v1.x; af1[5] = (_Float16)v1.y; af1[6] = (_Float16)v1.z; af1[7] = (_Float16)v1.w;
    __syncthreads();
#pragma unroll
    for (int j = 0; j < 8; ++j) {
      f16x8 bf = read_B(Bs, wn + j * 16 + lrow, quad);
      acc[0][j] = __builtin_amdgcn_mfma_f32_16x16x32_f16(af0, bf, acc[0][j], 0, 0, 0);
      acc[1][j] = __builtin_amdgcn_mfma_f32_16x16x32_f16(af1, bf, acc[1][j], 0, 0, 0);
    }
    __syncthreads();
  }
  // H epilogue -> Hs
#pragma unroll
  for (int i = 0; i < 2; ++i) {
    int rb = wm + i * 16 + quad * 4;
#pragma unroll
    for (int j = 0; j < 8; ++j) {
      int col = wn + j * 16 + lrow;
      float bv = bb[col];
#pragma unroll
      for (int reg = 0; reg < 4; ++reg) {
        Hs[(rb + reg) * 264 + col] = (_Float16)fmaxf(acc[i][j][reg] + bv, 0.f);
        acc[i][j][reg] = 0.f;
      }
    }
  }
  __syncthreads();

  // ---- layer 2 (tied W): A from Hs (LDS), B from LDS ----
#pragma unroll
  for (int kc = 0; kc < 8; ++kc) {
    stage_W<256>(Wb, kc * 32, 256, Bs, wave, lane);
    f16x8 af0 = *(const f16x8*)(Hs + (wm + lrow) * 264 + kc * 32 + quad * 8);
    f16x8 af1 = *(const f16x8*)(Hs + (wm + 16 + lrow) * 264 + kc * 32 + quad * 8);
    __syncthreads();
#pragma unroll
    for (int j = 0; j < 8; ++j) {
      f16x8 bf = read_B(Bs, wn + j * 16 + lrow, quad);
      acc[0][j] = __builtin_amdgcn_mfma_f32_16x16x32_f16(af0, bf, acc[0][j], 0, 0, 0);
      acc[1][j] = __builtin_amdgcn_mfma_f32_16x16x32_f16(af1, bf, acc[1][j], 0, 0, 0);
    }
    __syncthreads();
  }
  // M epilogue -> global
  _Float16* Mo = Mh + (size_t)z * (N_NODES * D);
#pragma unroll
  for (int i = 0; i < 2; ++i) {
    int rb = m0 + wm + i * 16 + quad * 4;
#pragma unroll
    for (int j = 0; j < 8; ++j) {
      int col = wn + j * 16 + lrow;
      float bv = bb[col];
#pragma unroll
      for (int reg = 0; reg < 4; ++reg) {
        int gm = rb + reg;
        if (gm < N_NODES)
          Mo[(size_t)gm * D + col] = (_Float16)fmaxf(acc[i][j][reg] + bv, 0.f);
      }
    }
  }
}

// ---------- aggregation: one block (4 waves) per node; waves split edges; LDS reduce ----------
__global__ __launch_bounds__(256) void agg_kernel(const int* __restrict__ offs,
                                                  const unsigned int* __restrict__ rowoff,
                                                  const _Float16* __restrict__ Mh,
                                                  _Float16* __restrict__ aggh) {
  __shared__ float part[4][256];
  const int node = blockIdx.x;
  const int wave = threadIdx.x >> 6, lane = threadIdx.x & 63;
  float a0 = 0.f, a1 = 0.f, a2 = 0.f, a3 = 0.f;
  const int beg = offs[node], end = offs[node + 1];
  for (int j = beg + wave; j < end; j += 4) {
    unsigned int off = rowoff[j];
    f16x4 v = *(const f16x4*)(Mh + (size_t)off + lane * 4);
    a0 += (float)v[0]; a1 += (float)v[1]; a2 += (float)v[2]; a3 += (float)v[3];
  }
  *(float4*)&part[wave][lane * 4] = make_float4(a0, a1, a2, a3);
  __syncthreads();
  if (wave == 0) {
    float4 p0 = *(const float4*)&part[0][lane * 4];
    float4 p1 = *(const float4*)&part[1][lane * 4];
    float4 p2 = *(const float4*)&part[2][lane * 4];
    float4 p3 = *(const float4*)&part[3][lane * 4];
    f16x4 o;
    o[0] = (_Float16)(p0.x + p1.x + p2.x + p3.x);
    o[1] = (_Float16)(p0.y + p1.y + p2.y + p3.y);
    o[2] = (_Float16)(p0.z + p1.z + p2.z + p3.z);
    o[3] = (_Float16)(p0.w + p1.w + p2.w + p3.w);
    *(f16x4*)(aggh + (size_t)node * D + lane * 4) = o;
  }
}

// ---------- fused gates GEMM + LSTM + 3-layer MLP ----------
// grid 625 x 256 thr (4 waves); block = 16 node rows; gates N=768 split 192 cols/wave.
__global__ __launch_bounds__(256) void tail_fused(
    const _Float16* __restrict__ aggh,
    const _Float16* __restrict__ Wg, const float* __restrict__ bg,
    const _Float16* __restrict__ W1h, const float* __restrict__ b1,
    const _Float16* __restrict__ W2h, const float* __restrict__ b2,
    const _Float16* __restrict__ W3h, const float* __restrict__ b3,
    float* __restrict__ out)
{
  __shared__ _Float16 Gs[16 * 776];   // 24,832 B
  __shared__ _Float16 Hn[16 * 264];   //  8,448
  __shared__ _Float16 Xs[16 * 136];   //  4,352
  __shared__ _Float16 X2s[16 * 136];  //  4,352
  const int t = threadIdx.x;
  const int wave = t >> 6, lane = t & 63;
  const int quad = lane >> 4, lrow = lane & 15;
  const int r0 = blockIdx.x * 16;     // 625*16 == 10000

  // A-frags from agg rows (16 B/lane, reused across all gate tiles)
  f16x8 af[8];
#pragma unroll
  for (int kc = 0; kc < 8; ++kc)
    af[kc] = *(const f16x8*)(aggh + (size_t)(r0 + lrow) * 256 + kc * 32 + quad * 8);

  // ---- gates: wave w covers cols w*192 .. w*192+191 (12 tiles) ----
  {
    f32x4 acc[12];
#pragma unroll
    for (int j = 0; j < 12; ++j) acc[j] = (f32x4)0.0f;
#pragma unroll
    for (int kc = 0; kc < 8; ++kc)
#pragma unroll
      for (int j = 0; j < 12; ++j) {
        int wr = (wave * 12 + j) * 16 + lrow;
        f16x8 bf = *(const f16x8*)(Wg + (size_t)wr * 256 + kc * 32 + quad * 8);
        acc[j] = __builtin_amdgcn_mfma_f32_16x16x32_f16(af[kc], bf, acc[j], 0, 0, 0);
      }
#pragma unroll
    for (int j = 0; j < 12; ++j) {
      int col = (wave * 12 + j) * 16 + lrow;
      float bv = bg[col];
#pragma unroll
      for (int reg = 0; reg < 4; ++reg)
        Gs[(quad * 4 + reg) * 776 + col] = (_Float16)(acc[j][reg] + bv);
    }
  }
  __syncthreads();

  // ---- LSTM: hn = sigm(o) * tanh(sigm(i) * tanh(g)) ----
  {
    int row = t >> 4, d0 = (t & 15) * 16;
#pragma unroll
    for (int half = 0; half < 2; ++half) {
      int d = d0 + half * 8;
      f16x8 vi = *(const f16x8*)(Gs + row * 776 + d);
      f16x8 vg = *(const f16x8*)(Gs + row * 776 + 256 + d);
      f16x8 vo = *(const f16x8*)(Gs + row * 776 + 512 + d);
      f16x8 o;
#pragma unroll
      for (int e = 0; e < 8; ++e) {
        float c = fast_sigmoid((float)vi[e]) * fast_tanh((float)vg[e]);
        o[e] = (_Float16)(fast_sigmoid((float)vo[e]) * fast_tanh(c));
      }
      *(f16x8*)(Hn + row * 264 + d) = o;
    }
  }
  __syncthreads();

  // ---- x1 = relu(hn @ W1^T + b1): wave covers cols w*32..+31 (2 tiles) ----
  {
    f16x8 ah[8];
#pragma unroll
    for (int kc = 0; kc < 8; ++kc)
      ah[kc] = *(const f16x8*)(Hn + lrow * 264 + kc * 32 + quad * 8);
    f32x4 a1[2];
    a1[0] = (f32x4)0.0f; a1[1] = (f32x4)0.0f;
#pragma unroll
    for (int kc = 0; kc < 8; ++kc)
#pragma unroll
      for (int j = 0; j < 2; ++j) {
        int wr = wave * 32 + j * 16 + lrow;
        f16x8 bf = *(const f16x8*)(W1h + (size_t)wr * 256 + kc * 32 + quad * 8);
        a1[j] = __builtin_amdgcn_mfma_f32_16x16x32_f16(ah[kc], bf, a1[j], 0, 0, 0);
      }
#pragma unroll
    for (int j = 0; j < 2; ++j) {
      int col = wave * 32 + j * 16 + lrow;
      float bv = b1[col];
#pragma unroll
      for (int reg = 0; reg < 4; ++reg)
        Xs[(quad * 4 + reg) * 136 + col] = (_Float16)fmaxf(a1[j][reg] + bv, 0.f);
    }
  }
  __syncthreads();

  // ---- x2 = relu(x1 @ W2^T + b2): wave covers cols w*32..+31 ----
  {
    f16x8 ax[4];
#pragma unroll
    for (int kc = 0; kc < 4; ++kc)
      ax[kc] = *(const f16x8*)(Xs + lrow * 136 + kc * 32 + quad * 8);
    f32x4 a2[2];
    a2[0] = (f32x4)0.0f; a2[1] = (f32x4)0.0f;
#pragma unroll
    for (int kc = 0; kc < 4; ++kc)
#pragma unroll
      for (int j = 0; j < 2; ++j) {
        int wr = wave * 32 + j * 16 + lrow;
        f16x8 bf = *(const f16x8*)(W2h + (size_t)wr * 128 + kc * 32 + quad * 8);
        a2[j] = __builtin_amdgcn_mfma_f32_16x16x32_f16(ax[kc], bf, a2[j], 0, 0, 0);
      }
#pragma unroll
    for (int j = 0; j < 2; ++j) {
      int col = wave * 32 + j * 16 + lrow;
      float bv = b2[col];
#pragma unroll
      for (int reg = 0; reg < 4; ++reg)
        X2s[(quad * 4 + reg) * 136 + col] = (_Float16)fmaxf(a2[j][reg] + bv, 0.f);
    }
  }
  __syncthreads();

  // ---- out = x2 @ W3^T + b3: wave covers cols w*64..+63 (4 tiles), fp32 out ----
  {
    f16x8 aw[4];
#pragma unroll
    for (int kc = 0; kc < 4; ++kc)
      aw[kc] = *(const f16x8*)(X2s + lrow * 136 + kc * 32 + quad * 8);
    f32x4 ao[4];
#pragma unroll
    for (int j = 0; j < 4; ++j) ao[j] = (f32x4)0.0f;
#pragma unroll
    for (int kc = 0; kc < 4; ++kc)
#pragma unroll
      for (int j = 0; j < 4; ++j) {
        int wr = wave * 64 + j * 16 + lrow;
        f16x8 bf = *(const f16x8*)(W3h + (size_t)wr * 128 + kc * 32 + quad * 8);
        ao[j] = __builtin_amdgcn_mfma_f32_16x16x32_f16(aw[kc], bf, ao[j], 0, 0, 0);
      }
#pragma unroll
    for (int j = 0; j < 4; ++j) {
      int col = wave * 64 + j * 16 + lrow;
      float bv = b3[col];
#pragma unroll
      for (int reg = 0; reg < 4; ++reg)
        out[(size_t)(r0 + quad * 4 + reg) * 256 + col] = ao[j][reg] + bv;
    }
  }
}

// ---------- launch ----------
extern "C" void kernel_launch(void* const* d_in, const int* in_sizes, int n_in,
                              void* d_out, int out_size, void* d_ws, size_t ws_size,
                              hipStream_t stream) {
  const float* feat  = (const float*)d_in[0];
  const int* src = (const int*)d_in[1];
  const int* dst = (const int*)d_in[2];
  const int* rel = (const int*)d_in[3];
  const float* W_rel = (const float*)d_in[4];
  const float* b_rel = (const float*)d_in[5];
  const float* W_ih  = (const float*)d_in[6];
  const float* b_ih  = (const float*)d_in[7];
  const float* b_hh  = (const float*)d_in[8];
  const float* W1 = (const float*)d_in[9];
  const float* b1 = (const float*)d_in[10];
  const float* W2 = (const float*)d_in[11];
  const float* b2 = (const float*)d_in[12];
  const float* W3 = (const float*)d_in[13];
  const float* b3 = (const float*)d_in[14];
  float* out = (float*)d_out;

  char* ws = (char*)d_ws;
  _Float16* Mh   = (_Float16*)(ws);              // 10,240,000 B (2 rel slabs)
  _Float16* aggh = (_Float16*)(ws + 10240000);   //  5,120,000
  char* wsb = ws + 15360000;
  _Float16* W_relh = (_Float16*)(wsb);             // 262,144
  _Float16* Wg     = (_Float16*)(wsb + 262144);    // 393,216
  _Float16* W1h    = (_Float16*)(wsb + 655360);    // 65,536
  _Float16* W2h    = (_Float16*)(wsb + 720896);    // 32,768
  _Float16* W3h    = (_Float16*)(wsb + 753664);    // 65,536
  float*    bg     = (float*)(wsb + 819200);       // 3,072
  int*      cnt    = (int*)(wsb + 822272);         // 40,000
  int*      offs   = (int*)(wsb + 862272);         // 40,004 (+pad)
  int*      cursors= (int*)(wsb + 902280);         // 40,000
  unsigned int* rowoff = (unsigned int*)(wsb + 942280);  // 1,280,000

  (void)hipMemsetAsync(cnt, 0, N_NODES * sizeof(int), stream);
  prep_kernel<<<2853, 256, 0, stream>>>(W_rel, W_ih, b_ih, b_hh, W1, W2, W3,
                                        dst, cnt, W_relh, Wg, bg, W1h, W2h, W3h);
  scan_kernel<<<1, 1024, 0, stream>>>(cnt, offs, cursors, N_NODES);
  fill_kernel<<<1250, 256, 0, stream>>>(dst, src, rel, cursors, rowoff);

  // fused edge NN (both layers, both relations), LDS-staged B
  edge_fused<<<dim3(157, 2), 256, 0, stream>>>(feat, W_relh, b_rel, Mh);

  // scatter-sum via sorted gather
  agg_kernel<<<N_NODES, 256, 0, stream>>>(offs, rowoff, Mh, aggh);

  // fused gates GEMM + LSTM + MLP -> out
  tail_fused<<<625, 256, 0, stream>>>(aggh, Wg, bg, W1h, b1, W2h, b2, W3h, b3, out);
}

// Round 8
// 233.855 us; speedup vs baseline: 1.1886x; 1.0768x over previous
//
#include <hip/hip_runtime.h>
#include <hip/hip_bf16.h>

#define N_NODES 10000
#define N_EDGES 320000
#define D 256

typedef __attribute__((ext_vector_type(8))) _Float16 f16x8;
typedef __attribute__((ext_vector_type(4))) _Float16 f16x4;
typedef __attribute__((ext_vector_type(4))) float f32x4;

__device__ __forceinline__ void async_copy16(const void* g, void* l) {
  __builtin_amdgcn_global_load_lds(
      (const __attribute__((address_space(1))) unsigned int*)g,
      (__attribute__((address_space(3))) unsigned int*)l, 16, 0, 0);
}

// stage W[ROWS][*] k-chunk (32 cols) into Bs[ROWS*32] with XOR quad swizzle
template<int ROWS>
__device__ __forceinline__ void stage_W(const _Float16* __restrict__ Wb, int k0, int K,
                                        _Float16* Bs, int wave, int lane) {
  const int sr = lane >> 2, ss = lane & 3;
#pragma unroll
  for (int s = 0; s < ROWS / 64; ++s) {
    int grp = wave + 4 * s;
    int r = grp * 16 + sr;
    int gq = ss ^ ((r >> 1) & 3);
    async_copy16(Wb + (size_t)r * K + k0 + gq * 8, Bs + grp * 512);
  }
}
__device__ __forceinline__ f16x8 read_B(const _Float16* Bs, int r, int quad) {
  return *(const f16x8*)(Bs + r * 32 + (quad ^ ((r >> 1) & 3)) * 8);
}

__device__ __forceinline__ float fast_sigmoid(float x) {
  return __builtin_amdgcn_rcpf(1.f + __expf(-x));
}
__device__ __forceinline__ float fast_tanh(float x) {
  float ax = fabsf(x);
  float e = __expf(-2.f * ax);
  float t = (1.f - e) * __builtin_amdgcn_rcpf(1.f + e);
  return copysignf(t, x);
}

// ---------- prep ----------
__global__ void prep_kernel(const float* __restrict__ W_rel, const float* __restrict__ W_ih,
                            const float* __restrict__ b_ih, const float* __restrict__ b_hh,
                            const float* __restrict__ W1, const float* __restrict__ W2,
                            const float* __restrict__ W3,
                            const int* __restrict__ dst, int* __restrict__ cnt,
                            _Float16* W_relh, _Float16* Wg, float* bg,
                            _Float16* W1h, _Float16* W2h, _Float16* W3h) {
  int i = blockIdx.x * 256 + threadIdx.x;
  if (i < N_EDGES) { atomicAdd(&cnt[dst[i]], 1); return; }
  i -= N_EDGES;
  if (i < 131072) { W_relh[i] = (_Float16)W_rel[i]; return; }
  i -= 131072;
  if (i < 196608) {           // W_ih rows {0-255 (i), 512-767 (g), 768-1023 (o)}
    int n = i >> 8, k = i & 255;
    int m = (n < 256) ? n : n + 256;
    Wg[i] = (_Float16)W_ih[m * 256 + k]; return;
  }
  i -= 196608;
  if (i < 32768) { W1h[i] = (_Float16)W1[i]; return; }
  i -= 32768;
  if (i < 16384) { W2h[i] = (_Float16)W2[i]; return; }
  i -= 16384;
  if (i < 32768) { W3h[i] = (_Float16)W3[i]; return; }
  i -= 32768;
  if (i < 768) { int m = (i < 256) ? i : i + 256; bg[i] = b_ih[m] + b_hh[m]; }
}

// ---------- scan ----------
__global__ __launch_bounds__(1024) void scan_kernel(const int* __restrict__ cnt,
                                                    int* __restrict__ offs,
                                                    int* __restrict__ cursors, int n) {
  __shared__ int buf[1024];
  const int t = threadIdx.x;
  int loc[10];
  int s = 0;
  int base = t * 10;
#pragma unroll
  for (int q = 0; q < 10; ++q) {
    int i = base + q;
    int v = (i < n) ? cnt[i] : 0;
    loc[q] = s;
    s += v;
  }
  buf[t] = s;
  __syncthreads();
  for (int off = 1; off < 1024; off <<= 1) {
    int x = (t >= off) ? buf[t - off] : 0;
    __syncthreads();
    buf[t] += x;
    __syncthreads();
  }
  int excl = buf[t] - s;
#pragma unroll
  for (int q = 0; q < 10; ++q) {
    int i = base + q;
    if (i < n) { int o = excl + loc[q]; offs[i] = o; cursors[i] = o; }
  }
  if (t == 1023) offs[n] = buf[1023];
}

// ---------- fill ----------
__global__ void fill_kernel(const int* __restrict__ dst, const int* __restrict__ src,
                            const int* __restrict__ rel, int* __restrict__ cursors,
                            unsigned int* __restrict__ rowoff) {
  int e = blockIdx.x * blockDim.x + threadIdx.x;
  if (e < N_EDGES) {
    int pos = atomicAdd(&cursors[dst[e]], 1);
    rowoff[pos] = (unsigned int)((rel[e] * N_NODES + src[e]) * D);
  }
}

// ---------- fused edge NN v2 (unchanged, proven) ----------
__global__ __launch_bounds__(256) void edge_fused(
    const float* __restrict__ feat, const _Float16* __restrict__ W_relh,
    const float* __restrict__ b_rel, _Float16* __restrict__ Mh)
{
  __shared__ _Float16 Hs[64 * 264];
  __shared__ alignas(16) _Float16 Bs[256 * 32];
  const int t = threadIdx.x;
  const int wave = t >> 6, lane = t & 63;
  const int quad = lane >> 4, lrow = lane & 15;
  const int z = blockIdx.y;
  const int m0 = blockIdx.x * 64;
  const _Float16* Wb = W_relh + z * 65536;
  const float* bb = b_rel + z * 256;
  const int wm = (wave >> 1) * 32;
  const int wn = (wave & 1) * 128;

  int ar0 = m0 + wm + lrow;      if (ar0 > N_NODES - 1) ar0 = N_NODES - 1;
  int ar1 = m0 + wm + 16 + lrow; if (ar1 > N_NODES - 1) ar1 = N_NODES - 1;
  const float* fr0 = feat + (size_t)ar0 * 256;
  const float* fr1 = feat + (size_t)ar1 * 256;

  f32x4 acc[2][8];
#pragma unroll
  for (int i = 0; i < 2; ++i)
#pragma unroll
    for (int j = 0; j < 8; ++j) acc[i][j] = (f32x4)0.0f;

#pragma unroll
  for (int kc = 0; kc < 8; ++kc) {
    stage_W<256>(Wb, kc * 32, 256, Bs, wave, lane);
    float4 u0 = *(const float4*)(fr0 + kc * 32 + quad * 8);
    float4 u1 = *(const float4*)(fr0 + kc * 32 + quad * 8 + 4);
    float4 v0 = *(const float4*)(fr1 + kc * 32 + quad * 8);
    float4 v1 = *(const float4*)(fr1 + kc * 32 + quad * 8 + 4);
    f16x8 af0, af1;
    af0[0] = (_Float16)u0.x; af0[1] = (_Float16)u0.y; af0[2] = (_Float16)u0.z; af0[3] = (_Float16)u0.w;
    af0[4] = (_Float16)u1.x; af0[5] = (_Float16)u1.y; af0[6] = (_Float16)u1.z; af0[7] = (_Float16)u1.w;
    af1[0] = (_Float16)v0.x; af1[1] = (_Float16)v0.y; af1[2] = (_Float16)v0.z; af1[3] = (_Float16)v0.w;
    af1[4] = (_Float16)v1.x; af1[5] = (_Float16)v1.y; af1[6] = (_Float16)v1.z; af1[7] = (_Float16)v1.w;
    __syncthreads();
#pragma unroll
    for (int j = 0; j < 8; ++j) {
      f16x8 bf = read_B(Bs, wn + j * 16 + lrow, quad);
      acc[0][j] = __builtin_amdgcn_mfma_f32_16x16x32_f16(af0, bf, acc[0][j], 0, 0, 0);
      acc[1][j] = __builtin_amdgcn_mfma_f32_16x16x32_f16(af1, bf, acc[1][j], 0, 0, 0);
    }
    __syncthreads();
  }
#pragma unroll
  for (int i = 0; i < 2; ++i) {
    int rb = wm + i * 16 + quad * 4;
#pragma unroll
    for (int j = 0; j < 8; ++j) {
      int col = wn + j * 16 + lrow;
      float bv = bb[col];
#pragma unroll
      for (int reg = 0; reg < 4; ++reg) {
        Hs[(rb + reg) * 264 + col] = (_Float16)fmaxf(acc[i][j][reg] + bv, 0.f);
        acc[i][j][reg] = 0.f;
      }
    }
  }
  __syncthreads();

#pragma unroll
  for (int kc = 0; kc < 8; ++kc) {
    stage_W<256>(Wb, kc * 32, 256, Bs, wave, lane);
    f16x8 af0 = *(const f16x8*)(Hs + (wm + lrow) * 264 + kc * 32 + quad * 8);
    f16x8 af1 = *(const f16x8*)(Hs + (wm + 16 + lrow) * 264 + kc * 32 + quad * 8);
    __syncthreads();
#pragma unroll
    for (int j = 0; j < 8; ++j) {
      f16x8 bf = read_B(Bs, wn + j * 16 + lrow, quad);
      acc[0][j] = __builtin_amdgcn_mfma_f32_16x16x32_f16(af0, bf, acc[0][j], 0, 0, 0);
      acc[1][j] = __builtin_amdgcn_mfma_f32_16x16x32_f16(af1, bf, acc[1][j], 0, 0, 0);
    }
    __syncthreads();
  }
  _Float16* Mo = Mh + (size_t)z * (N_NODES * D);
#pragma unroll
  for (int i = 0; i < 2; ++i) {
    int rb = m0 + wm + i * 16 + quad * 4;
#pragma unroll
    for (int j = 0; j < 8; ++j) {
      int col = wn + j * 16 + lrow;
      float bv = bb[col];
#pragma unroll
      for (int reg = 0; reg < 4; ++reg) {
        int gm = rb + reg;
        if (gm < N_NODES)
          Mo[(size_t)gm * D + col] = (_Float16)fmaxf(acc[i][j][reg] + bv, 0.f);
      }
    }
  }
}

// ---------- aggregation ----------
__global__ __launch_bounds__(256) void agg_kernel(const int* __restrict__ offs,
                                                  const unsigned int* __restrict__ rowoff,
                                                  const _Float16* __restrict__ Mh,
                                                  _Float16* __restrict__ aggh) {
  __shared__ float part[4][256];
  const int node = blockIdx.x;
  const int wave = threadIdx.x >> 6, lane = threadIdx.x & 63;
  float a0 = 0.f, a1 = 0.f, a2 = 0.f, a3 = 0.f;
  const int beg = offs[node], end = offs[node + 1];
  for (int j = beg + wave; j < end; j += 4) {
    unsigned int off = rowoff[j];
    f16x4 v = *(const f16x4*)(Mh + (size_t)off + lane * 4);
    a0 += (float)v[0]; a1 += (float)v[1]; a2 += (float)v[2]; a3 += (float)v[3];
  }
  *(float4*)&part[wave][lane * 4] = make_float4(a0, a1, a2, a3);
  __syncthreads();
  if (wave == 0) {
    float4 p0 = *(const float4*)&part[0][lane * 4];
    float4 p1 = *(const float4*)&part[1][lane * 4];
    float4 p2 = *(const float4*)&part[2][lane * 4];
    float4 p3 = *(const float4*)&part[3][lane * 4];
    f16x4 o;
    o[0] = (_Float16)(p0.x + p1.x + p2.x + p3.x);
    o[1] = (_Float16)(p0.y + p1.y + p2.y + p3.y);
    o[2] = (_Float16)(p0.z + p1.z + p2.z + p3.z);
    o[3] = (_Float16)(p0.w + p1.w + p2.w + p3.w);
    *(f16x4*)(aggh + (size_t)node * D + lane * 4) = o;
  }
}

// ---------- MFMA GEMM (gates): proven 128x128 LDS-staged path ----------
__global__ __launch_bounds__(256) void mfma_gemm(
    const _Float16* __restrict__ A, const _Float16* __restrict__ W,
    const float* __restrict__ bias, _Float16* __restrict__ Cout,
    int M, int N, int K)
{
  __shared__ alignas(16) _Float16 As[128 * 32];
  __shared__ alignas(16) _Float16 Bs[128 * 32];
  const int t = threadIdx.x;
  const int wave = t >> 6, lane = t & 63;
  const int m0 = blockIdx.y * 128, n0 = blockIdx.x * 128;
  const int wm = (wave >> 1) * 64, wn = (wave & 1) * 64;
  const int lrow = lane & 15, quad = lane >> 4;

  f32x4 acc[4][4];
#pragma unroll
  for (int i = 0; i < 4; ++i)
#pragma unroll
    for (int j = 0; j < 4; ++j) acc[i][j] = (f32x4)0.0f;

  const int sr_loc = lane >> 2;
  const int sslot  = lane & 3;

  for (int k0 = 0; k0 < K; k0 += 32) {
#pragma unroll
    for (int s = 0; s < 2; ++s) {
      int t8 = wave + 4 * s;
      int r  = t8 * 16 + sr_loc;
      int gq = sslot ^ ((r >> 1) & 3);
      int grr = m0 + r; if (grr > M - 1) grr = M - 1;
      async_copy16(A + (size_t)grr * K + k0 + gq * 8, As + t8 * 512);
      int gn = n0 + r;
      async_copy16(W + (size_t)gn * K + k0 + gq * 8, Bs + t8 * 512);
    }
    __syncthreads();
    f16x8 af[4], bfr[4];
#pragma unroll
    for (int i = 0; i < 4; ++i) af[i] = read_B(As, wm + i * 16 + lrow, quad);
#pragma unroll
    for (int j = 0; j < 4; ++j) bfr[j] = read_B(Bs, wn + j * 16 + lrow, quad);
#pragma unroll
    for (int i = 0; i < 4; ++i)
#pragma unroll
      for (int j = 0; j < 4; ++j)
        acc[i][j] = __builtin_amdgcn_mfma_f32_16x16x32_f16(af[i], bfr[j], acc[i][j], 0, 0, 0);
    __syncthreads();
  }

#pragma unroll
  for (int i = 0; i < 4; ++i) {
    int rbase = m0 + wm + i * 16 + quad * 4;
#pragma unroll
    for (int j = 0; j < 4; ++j) {
      int col = n0 + wn + j * 16 + lrow;
      float bv = bias[col];
#pragma unroll
      for (int reg = 0; reg < 4; ++reg) {
        int gm = rbase + reg;
        if (gm < M) Cout[(size_t)gm * N + col] = (_Float16)(acc[i][j][reg] + bv);
      }
    }
  }
}

// ---------- mlp_fused v3: LSTM + 3 MLP layers, LDS-staged weights ----------
// grid 313 x 256 thr; block = 32 node rows; waves: rh=(w>>1) row-half, ch=(w&1) col-half.
__global__ __launch_bounds__(256) void mlp_fused(
    const _Float16* __restrict__ gatesh,
    const _Float16* __restrict__ W1h, const float* __restrict__ b1,
    const _Float16* __restrict__ W2h, const float* __restrict__ b2,
    const _Float16* __restrict__ W3h, const float* __restrict__ b3,
    float* __restrict__ out)
{
  __shared__ _Float16 Hn[32 * 264];              // 16,896 B
  __shared__ _Float16 Xs[32 * 136];              //  8,704
  __shared__ _Float16 X2s[32 * 136];             //  8,704
  __shared__ alignas(16) _Float16 Bs[256 * 32];  // 16,384
  const int t = threadIdx.x;
  const int wave = t >> 6, lane = t & 63;
  const int quad = lane >> 4, lrow = lane & 15;
  const int rh = (wave >> 1) * 16;    // 0 or 16
  const int ch = wave & 1;
  const int r0 = blockIdx.x * 32;

  // ---- LSTM: hn = sigm(o)*tanh(sigm(i)*tanh(g)) ; gates (i,g,o) from global ----
  {
    int row = t >> 3, seg = t & 7;
    int gr = r0 + row; if (gr > N_NODES - 1) gr = N_NODES - 1;
    const _Float16* g = gatesh + (size_t)gr * 768 + seg * 32;
#pragma unroll
    for (int half = 0; half < 4; ++half) {
      int d = half * 8;
      f16x8 vi = *(const f16x8*)(g + d);
      f16x8 vg = *(const f16x8*)(g + 256 + d);
      f16x8 vo = *(const f16x8*)(g + 512 + d);
      f16x8 o;
#pragma unroll
      for (int e = 0; e < 8; ++e) {
        float c = fast_sigmoid((float)vi[e]) * fast_tanh((float)vg[e]);
        o[e] = (_Float16)(fast_sigmoid((float)vo[e]) * fast_tanh(c));
      }
      *(f16x8*)(Hn + row * 264 + seg * 32 + d) = o;
    }
  }
  __syncthreads();

  // ---- x1 = relu(hn @ W1^T + b1): N=128, K=256; wave: rows rh..rh+15, cols ch*64..+63 ----
  {
    f32x4 acc[4];
#pragma unroll
    for (int j = 0; j < 4; ++j) acc[j] = (f32x4)0.0f;
#pragma unroll
    for (int kc = 0; kc < 8; ++kc) {
      stage_W<128>(W1h, kc * 32, 256, Bs, wave, lane);
      f16x8 af = *(const f16x8*)(Hn + (rh + lrow) * 264 + kc * 32 + quad * 8);
      __syncthreads();
#pragma unroll
      for (int j = 0; j < 4; ++j) {
        f16x8 bf = read_B(Bs, ch * 64 + j * 16 + lrow, quad);
        acc[j] = __builtin_amdgcn_mfma_f32_16x16x32_f16(af, bf, acc[j], 0, 0, 0);
      }
      __syncthreads();
    }
#pragma unroll
    for (int j = 0; j < 4; ++j) {
      int col = ch * 64 + j * 16 + lrow;
      float bv = b1[col];
#pragma unroll
      for (int reg = 0; reg < 4; ++reg)
        Xs[(rh + quad * 4 + reg) * 136 + col] = (_Float16)fmaxf(acc[j][reg] + bv, 0.f);
    }
  }
  __syncthreads();

  // ---- x2 = relu(x1 @ W2^T + b2): N=128, K=128 ----
  {
    f32x4 acc[4];
#pragma unroll
    for (int j = 0; j < 4; ++j) acc[j] = (f32x4)0.0f;
#pragma unroll
    for (int kc = 0; kc < 4; ++kc) {
      stage_W<128>(W2h, kc * 32, 128, Bs, wave, lane);
      f16x8 af = *(const f16x8*)(Xs + (rh + lrow) * 136 + kc * 32 + quad * 8);
      __syncthreads();
#pragma unroll
      for (int j = 0; j < 4; ++j) {
        f16x8 bf = read_B(Bs, ch * 64 + j * 16 + lrow, quad);
        acc[j] = __builtin_amdgcn_mfma_f32_16x16x32_f16(af, bf, acc[j], 0, 0, 0);
      }
      __syncthreads();
    }
#pragma unroll
    for (int j = 0; j < 4; ++j) {
      int col = ch * 64 + j * 16 + lrow;
      float bv = b2[col];
#pragma unroll
      for (int reg = 0; reg < 4; ++reg)
        X2s[(rh + quad * 4 + reg) * 136 + col] = (_Float16)fmaxf(acc[j][reg] + bv, 0.f);
    }
  }
  __syncthreads();

  // ---- out = x2 @ W3^T + b3: N=256, K=128, fp32 out; wave cols ch*128..+127 ----
  {
    f32x4 acc[8];
#pragma unroll
    for (int j = 0; j < 8; ++j) acc[j] = (f32x4)0.0f;
#pragma unroll
    for (int kc = 0; kc < 4; ++kc) {
      stage_W<256>(W3h, kc * 32, 128, Bs, wave, lane);
      f16x8 af = *(const f16x8*)(X2s + (rh + lrow) * 136 + kc * 32 + quad * 8);
      __syncthreads();
#pragma unroll
      for (int j = 0; j < 8; ++j) {
        f16x8 bf = read_B(Bs, ch * 128 + j * 16 + lrow, quad);
        acc[j] = __builtin_amdgcn_mfma_f32_16x16x32_f16(af, bf, acc[j], 0, 0, 0);
      }
      __syncthreads();
    }
#pragma unroll
    for (int j = 0; j < 8; ++j) {
      int col = ch * 128 + j * 16 + lrow;
      float bv = b3[col];
#pragma unroll
      for (int reg = 0; reg < 4; ++reg) {
        int gm = r0 + rh + quad * 4 + reg;
        if (gm < N_NODES) out[(size_t)gm * 256 + col] = acc[j][reg] + bv;
      }
    }
  }
}

// ---------- launch ----------
extern "C" void kernel_launch(void* const* d_in, const int* in_sizes, int n_in,
                              void* d_out, int out_size, void* d_ws, size_t ws_size,
                              hipStream_t stream) {
  const float* feat  = (const float*)d_in[0];
  const int* src = (const int*)d_in[1];
  const int* dst = (const int*)d_in[2];
  const int* rel = (const int*)d_in[3];
  const float* W_rel = (const float*)d_in[4];
  const float* b_rel = (const float*)d_in[5];
  const float* W_ih  = (const float*)d_in[6];
  const float* b_ih  = (const float*)d_in[7];
  const float* b_hh  = (const float*)d_in[8];
  const float* W1 = (const float*)d_in[9];
  const float* b1 = (const float*)d_in[10];
  const float* W2 = (const float*)d_in[11];
  const float* b2 = (const float*)d_in[12];
  const float* W3 = (const float*)d_in[13];
  const float* b3 = (const float*)d_in[14];
  float* out = (float*)d_out;

  char* ws = (char*)d_ws;
  _Float16* Mh     = (_Float16*)(ws);              // 10,240,000 B (2 rel slabs)
  _Float16* aggh   = (_Float16*)(ws + 10240000);   //  5,120,000
  _Float16* gatesh = (_Float16*)(ws + 15360000);   // 15,360,000
  char* wsb = ws + 30720000;
  _Float16* W_relh = (_Float16*)(wsb);             // 262,144
  _Float16* Wg     = (_Float16*)(wsb + 262144);    // 393,216
  _Float16* W1h    = (_Float16*)(wsb + 655360);    // 65,536
  _Float16* W2h    = (_Float16*)(wsb + 720896);    // 32,768
  _Float16* W3h    = (_Float16*)(wsb + 753664);    // 65,536
  float*    bg     = (float*)(wsb + 819200);       // 3,072
  int*      cnt    = (int*)(wsb + 822272);         // 40,000
  int*      offs   = (int*)(wsb + 862272);         // 40,004 (+pad)
  int*      cursors= (int*)(wsb + 902280);         // 40,000
  unsigned int* rowoff = (unsigned int*)(wsb + 942280);  // 1,280,000

  (void)hipMemsetAsync(cnt, 0, N_NODES * sizeof(int), stream);
  prep_kernel<<<2853, 256, 0, stream>>>(W_rel, W_ih, b_ih, b_hh, W1, W2, W3,
                                        dst, cnt, W_relh, Wg, bg, W1h, W2h, W3h);
  scan_kernel<<<1, 1024, 0, stream>>>(cnt, offs, cursors, N_NODES);
  fill_kernel<<<1250, 256, 0, stream>>>(dst, src, rel, cursors, rowoff);

  // fused edge NN (both layers, both relations), LDS-staged B
  edge_fused<<<dim3(157, 2), 256, 0, stream>>>(feat, W_relh, b_rel, Mh);

  // scatter-sum via sorted gather
  agg_kernel<<<N_NODES, 256, 0, stream>>>(offs, rowoff, Mh, aggh);

  // gates (i,g,o) = agg @ Wg^T + bg  (proven LDS-staged GEMM)
  mfma_gemm<<<dim3(6, 79), 256, 0, stream>>>(aggh, Wg, bg, gatesh, N_NODES, 768, 256);

  // LSTM + MLP -> out (LDS-staged weights)
  mlp_fused<<<313, 256, 0, stream>>>(gatesh, W1h, b1, W2h, b2, W3h, b3, out);
}

// Round 9
// 233.383 us; speedup vs baseline: 1.1910x; 1.0020x over previous
//
#include <hip/hip_runtime.h>
#include <hip/hip_bf16.h>

#define N_NODES 10000
#define N_EDGES 320000
#define D 256

typedef __attribute__((ext_vector_type(8))) _Float16 f16x8;
typedef __attribute__((ext_vector_type(4))) _Float16 f16x4;
typedef __attribute__((ext_vector_type(4))) float f32x4;

__device__ __forceinline__ void async_copy16(const void* g, void* l) {
  __builtin_amdgcn_global_load_lds(
      (const __attribute__((address_space(1))) unsigned int*)g,
      (__attribute__((address_space(3))) unsigned int*)l, 16, 0, 0);
}

// stage ROWS x 32 f16 k-chunk into Bs[ROWS*32] with XOR quad swizzle; WAVES waves cooperate
template<int ROWS, int WAVES>
__device__ __forceinline__ void stage_tile(const _Float16* __restrict__ Wb, int k0, int K,
                                           _Float16* Bs, int wave, int lane) {
  const int sr = lane >> 2, ss = lane & 3;
  for (int grp = wave; grp < ROWS / 16; grp += WAVES) {
    int r = grp * 16 + sr;
    int gq = ss ^ ((r >> 1) & 3);
    async_copy16(Wb + (size_t)r * K + k0 + gq * 8, Bs + grp * 512);
  }
}
// same but clamps global row to [0, M)
template<int ROWS, int WAVES>
__device__ __forceinline__ void stage_tile_clamp(const _Float16* __restrict__ Ab, int m0, int M,
                                                 int k0, int K, _Float16* As, int wave, int lane) {
  const int sr = lane >> 2, ss = lane & 3;
  for (int grp = wave; grp < ROWS / 16; grp += WAVES) {
    int r = grp * 16 + sr;
    int gr = m0 + r; if (gr > M - 1) gr = M - 1;
    int gq = ss ^ ((r >> 1) & 3);
    async_copy16(Ab + (size_t)gr * K + k0 + gq * 8, As + grp * 512);
  }
}
__device__ __forceinline__ f16x8 read_B(const _Float16* Bs, int r, int quad) {
  return *(const f16x8*)(Bs + r * 32 + (quad ^ ((r >> 1) & 3)) * 8);
}

__device__ __forceinline__ float fast_sigmoid(float x) {
  return __builtin_amdgcn_rcpf(1.f + __expf(-x));
}
__device__ __forceinline__ float fast_tanh(float x) {
  float ax = fabsf(x);
  float e = __expf(-2.f * ax);
  float t = (1.f - e) * __builtin_amdgcn_rcpf(1.f + e);
  return copysignf(t, x);
}

// ---------- prep: cast weights to fp16; Wg packed as (i,g,o) 16-col triples; hist ----------
__global__ void prep_kernel(const float* __restrict__ W_rel, const float* __restrict__ W_ih,
                            const float* __restrict__ b_ih, const float* __restrict__ b_hh,
                            const float* __restrict__ W1, const float* __restrict__ W2,
                            const float* __restrict__ W3,
                            const int* __restrict__ dst, int* __restrict__ cnt,
                            _Float16* W_relh, _Float16* Wg, float* bg,
                            _Float16* W1h, _Float16* W2h, _Float16* W3h) {
  int i = blockIdx.x * 256 + threadIdx.x;
  if (i < N_EDGES) { atomicAdd(&cnt[dst[i]], 1); return; }
  i -= N_EDGES;
  if (i < 131072) { W_relh[i] = (_Float16)W_rel[i]; return; }
  i -= 131072;
  if (i < 196608) {
    // packed row p = 48t + 16*phase + u  ->  W_ih row (16t+u) + {0,512,768}[phase]
    int p = i >> 8, k = i & 255;
    int t = p / 48, rem = p - t * 48;
    int phase = rem >> 4, u = rem & 15;
    int orig = t * 16 + u + (phase == 1 ? 512 : (phase == 2 ? 768 : 0));
    Wg[i] = (_Float16)W_ih[orig * 256 + k]; return;
  }
  i -= 196608;
  if (i < 32768) { W1h[i] = (_Float16)W1[i]; return; }
  i -= 32768;
  if (i < 16384) { W2h[i] = (_Float16)W2[i]; return; }
  i -= 16384;
  if (i < 32768) { W3h[i] = (_Float16)W3[i]; return; }
  i -= 32768;
  if (i < 768) {
    int t = i / 48, rem = i - t * 48;
    int phase = rem >> 4, u = rem & 15;
    int orig = t * 16 + u + (phase == 1 ? 512 : (phase == 2 ? 768 : 0));
    bg[i] = b_ih[orig] + b_hh[orig];
  }
}

// ---------- scan ----------
__global__ __launch_bounds__(1024) void scan_kernel(const int* __restrict__ cnt,
                                                    int* __restrict__ offs,
                                                    int* __restrict__ cursors, int n) {
  __shared__ int buf[1024];
  const int t = threadIdx.x;
  int loc[10];
  int s = 0;
  int base = t * 10;
#pragma unroll
  for (int q = 0; q < 10; ++q) {
    int i = base + q;
    int v = (i < n) ? cnt[i] : 0;
    loc[q] = s;
    s += v;
  }
  buf[t] = s;
  __syncthreads();
  for (int off = 1; off < 1024; off <<= 1) {
    int x = (t >= off) ? buf[t - off] : 0;
    __syncthreads();
    buf[t] += x;
    __syncthreads();
  }
  int excl = buf[t] - s;
#pragma unroll
  for (int q = 0; q < 10; ++q) {
    int i = base + q;
    if (i < n) { int o = excl + loc[q]; offs[i] = o; cursors[i] = o; }
  }
  if (t == 1023) offs[n] = buf[1023];
}

// ---------- fill ----------
__global__ void fill_kernel(const int* __restrict__ dst, const int* __restrict__ src,
                            const int* __restrict__ rel, int* __restrict__ cursors,
                            unsigned int* __restrict__ rowoff) {
  int e = blockIdx.x * blockDim.x + threadIdx.x;
  if (e < N_EDGES) {
    int pos = atomicAdd(&cursors[dst[e]], 1);
    rowoff[pos] = (unsigned int)((rel[e] * N_NODES + src[e]) * D);
  }
}

// ---------- fused edge NN v3: 512 threads (8 waves), LDS-staged W ----------
// grid (157, 2); block = 64 rows x 256 cols; wave = 32 rows x 64 cols.
__global__ __launch_bounds__(512) void edge_fused(
    const float* __restrict__ feat, const _Float16* __restrict__ W_relh,
    const float* __restrict__ b_rel, _Float16* __restrict__ Mh)
{
  __shared__ _Float16 Hs[64 * 266];              // 34,048 B
  __shared__ alignas(16) _Float16 Bs[256 * 32];  // 16,384 B
  const int t = threadIdx.x;
  const int wave = t >> 6, lane = t & 63;
  const int quad = lane >> 4, lrow = lane & 15;
  const int z = blockIdx.y;
  const int m0 = blockIdx.x * 64;
  const _Float16* Wb = W_relh + z * 65536;
  const float* bb = b_rel + z * 256;
  const int wm = (wave >> 2) * 32;   // 0 or 32
  const int wn = (wave & 3) * 64;    // 0,64,128,192

  int ar0 = m0 + wm + lrow;      if (ar0 > N_NODES - 1) ar0 = N_NODES - 1;
  int ar1 = m0 + wm + 16 + lrow; if (ar1 > N_NODES - 1) ar1 = N_NODES - 1;
  const float* fr0 = feat + (size_t)ar0 * 256;
  const float* fr1 = feat + (size_t)ar1 * 256;

  f32x4 acc[2][4];
#pragma unroll
  for (int i = 0; i < 2; ++i)
#pragma unroll
    for (int j = 0; j < 4; ++j) acc[i][j] = (f32x4)0.0f;

  // ---- layer 1: A from global fp32 (cvt), B from LDS ----
#pragma unroll
  for (int kc = 0; kc < 8; ++kc) {
    stage_tile<256, 8>(Wb, kc * 32, 256, Bs, wave, lane);
    float4 u0 = *(const float4*)(fr0 + kc * 32 + quad * 8);
    float4 u1 = *(const float4*)(fr0 + kc * 32 + quad * 8 + 4);
    float4 v0 = *(const float4*)(fr1 + kc * 32 + quad * 8);
    float4 v1 = *(const float4*)(fr1 + kc * 32 + quad * 8 + 4);
    f16x8 af0, af1;
    af0[0] = (_Float16)u0.x; af0[1] = (_Float16)u0.y; af0[2] = (_Float16)u0.z; af0[3] = (_Float16)u0.w;
    af0[4] = (_Float16)u1.x; af0[5] = (_Float16)u1.y; af0[6] = (_Float16)u1.z; af0[7] = (_Float16)u1.w;
    af1[0] = (_Float16)v0.x; af1[1] = (_Float16)v0.y; af1[2] = (_Float16)v0.z; af1[3] = (_Float16)v0.w;
    af1[4] = (_Float16)v1.x; af1[5] = (_Float16)v1.y; af1[6] = (_Float16)v1.z; af1[7] = (_Float16)v1.w;
    __syncthreads();
#pragma unroll
    for (int j = 0; j < 4; ++j) {
      f16x8 bf = read_B(Bs, wn + j * 16 + lrow, quad);
      acc[0][j] = __builtin_amdgcn_mfma_f32_16x16x32_f16(af0, bf, acc[0][j], 0, 0, 0);
      acc[1][j] = __builtin_amdgcn_mfma_f32_16x16x32_f16(af1, bf, acc[1][j], 0, 0, 0);
    }
    __syncthreads();
  }
  // H epilogue -> Hs
#pragma unroll
  for (int i = 0; i < 2; ++i) {
    int rb = wm + i * 16 + quad * 4;
#pragma unroll
    for (int j = 0; j < 4; ++j) {
      int col = wn + j * 16 + lrow;
      float bv = bb[col];
#pragma unroll
      for (int reg = 0; reg < 4; ++reg) {
        Hs[(rb + reg) * 266 + col] = (_Float16)fmaxf(acc[i][j][reg] + bv, 0.f);
        acc[i][j][reg] = 0.f;
      }
    }
  }
  __syncthreads();

  // ---- layer 2 (tied W): A from Hs ----
#pragma unroll
  for (int kc = 0; kc < 8; ++kc) {
    stage_tile<256, 8>(Wb, kc * 32, 256, Bs, wave, lane);
    f16x8 af0 = *(const f16x8*)(Hs + (wm + lrow) * 266 + kc * 32 + quad * 8);
    f16x8 af1 = *(const f16x8*)(Hs + (wm + 16 + lrow) * 266 + kc * 32 + quad * 8);
    __syncthreads();
#pragma unroll
    for (int j = 0; j < 4; ++j) {
      f16x8 bf = read_B(Bs, wn + j * 16 + lrow, quad);
      acc[0][j] = __builtin_amdgcn_mfma_f32_16x16x32_f16(af0, bf, acc[0][j], 0, 0, 0);
      acc[1][j] = __builtin_amdgcn_mfma_f32_16x16x32_f16(af1, bf, acc[1][j], 0, 0, 0);
    }
    __syncthreads();
  }
  _Float16* Mo = Mh + (size_t)z * (N_NODES * D);
#pragma unroll
  for (int i = 0; i < 2; ++i) {
    int rb = m0 + wm + i * 16 + quad * 4;
#pragma unroll
    for (int j = 0; j < 4; ++j) {
      int col = wn + j * 16 + lrow;
      float bv = bb[col];
#pragma unroll
      for (int reg = 0; reg < 4; ++reg) {
        int gm = rb + reg;
        if (gm < N_NODES)
          Mo[(size_t)gm * D + col] = (_Float16)fmaxf(acc[i][j][reg] + bv, 0.f);
      }
    }
  }
}

// ---------- aggregation (unchanged) ----------
__global__ __launch_bounds__(256) void agg_kernel(const int* __restrict__ offs,
                                                  const unsigned int* __restrict__ rowoff,
                                                  const _Float16* __restrict__ Mh,
                                                  _Float16* __restrict__ aggh) {
  __shared__ float part[4][256];
  const int node = blockIdx.x;
  const int wave = threadIdx.x >> 6, lane = threadIdx.x & 63;
  float a0 = 0.f, a1 = 0.f, a2 = 0.f, a3 = 0.f;
  const int beg = offs[node], end = offs[node + 1];
  for (int j = beg + wave; j < end; j += 4) {
    unsigned int off = rowoff[j];
    f16x4 v = *(const f16x4*)(Mh + (size_t)off + lane * 4);
    a0 += (float)v[0]; a1 += (float)v[1]; a2 += (float)v[2]; a3 += (float)v[3];
  }
  *(float4*)&part[wave][lane * 4] = make_float4(a0, a1, a2, a3);
  __syncthreads();
  if (wave == 0) {
    float4 p0 = *(const float4*)&part[0][lane * 4];
    float4 p1 = *(const float4*)&part[1][lane * 4];
    float4 p2 = *(const float4*)&part[2][lane * 4];
    float4 p3 = *(const float4*)&part[3][lane * 4];
    f16x4 o;
    o[0] = (_Float16)(p0.x + p1.x + p2.x + p3.x);
    o[1] = (_Float16)(p0.y + p1.y + p2.y + p3.y);
    o[2] = (_Float16)(p0.z + p1.z + p2.z + p3.z);
    o[3] = (_Float16)(p0.w + p1.w + p2.w + p3.w);
    *(f16x4*)(aggh + (size_t)node * D + lane * 4) = o;
  }
}

// ---------- gates GEMM + LSTM epilogue: hn = sigm(o)*tanh(sigm(i)*tanh(g)) ----------
// Wg packed in (i,g,o) 16-col triples. grid (8, 79); block = 128 rows x 96 packed cols;
// wave = 64 rows x 48 cols (one triple): col-tiles j=0,1,2 are i,g,o of d-group t.
__global__ __launch_bounds__(256) void gates_lstm(
    const _Float16* __restrict__ aggh, const _Float16* __restrict__ Wg,
    const float* __restrict__ bg, _Float16* __restrict__ hnh)
{
  __shared__ alignas(16) _Float16 As[128 * 32];  // 8,192 B
  __shared__ alignas(16) _Float16 Ws[96 * 32];   // 6,144 B
  const int t = threadIdx.x;
  const int wave = t >> 6, lane = t & 63;
  const int quad = lane >> 4, lrow = lane & 15;
  const int m0 = blockIdx.y * 128;
  const int n0 = blockIdx.x * 96;
  const int wm = (wave >> 1) * 64;   // 0 or 64
  const int wn = (wave & 1) * 48;    // 0 or 48
  const int tg = (n0 + wn) / 48;     // d-group 0..15

  f32x4 acc[4][3];
#pragma unroll
  for (int i = 0; i < 4; ++i)
#pragma unroll
    for (int j = 0; j < 3; ++j) acc[i][j] = (f32x4)0.0f;

#pragma unroll
  for (int kc = 0; kc < 8; ++kc) {
    stage_tile_clamp<128, 4>(aggh, m0, N_NODES, kc * 32, 256, As, wave, lane);
    stage_tile<96, 4>(Wg + (size_t)n0 * 256, kc * 32, 256, Ws, wave, lane);
    __syncthreads();
    f16x8 af[4], bf[3];
#pragma unroll
    for (int i = 0; i < 4; ++i) af[i] = read_B(As, wm + i * 16 + lrow, quad);
#pragma unroll
    for (int j = 0; j < 3; ++j) bf[j] = read_B(Ws, wn + j * 16 + lrow, quad);
#pragma unroll
    for (int i = 0; i < 4; ++i)
#pragma unroll
      for (int j = 0; j < 3; ++j)
        acc[i][j] = __builtin_amdgcn_mfma_f32_16x16x32_f16(af[i], bf[j], acc[i][j], 0, 0, 0);
    __syncthreads();
  }

  // LSTM epilogue: same (reg,lane)->(row,col) mapping across the 3 phase tiles
  float bvi = bg[n0 + wn + lrow];
  float bvg = bg[n0 + wn + 16 + lrow];
  float bvo = bg[n0 + wn + 32 + lrow];
  const int dcol = tg * 16 + lrow;
#pragma unroll
  for (int i = 0; i < 4; ++i) {
    int rb = m0 + wm + i * 16 + quad * 4;
#pragma unroll
    for (int reg = 0; reg < 4; ++reg) {
      int gm = rb + reg;
      if (gm < N_NODES) {
        float vi = acc[i][0][reg] + bvi;
        float vg = acc[i][1][reg] + bvg;
        float vo = acc[i][2][reg] + bvo;
        float c = fast_sigmoid(vi) * fast_tanh(vg);
        hnh[(size_t)gm * 256 + dcol] = (_Float16)(fast_sigmoid(vo) * fast_tanh(c));
      }
    }
  }
}

// ---------- mlp_fused v4: 3 MLP layers from hn, LDS-staged weights ----------
// grid 313 x 256 thr; block = 32 node rows; waves: rh=(w>>1)*16, ch=w&1.
__global__ __launch_bounds__(256) void mlp_fused(
    const _Float16* __restrict__ hnh,
    const _Float16* __restrict__ W1h, const float* __restrict__ b1,
    const _Float16* __restrict__ W2h, const float* __restrict__ b2,
    const _Float16* __restrict__ W3h, const float* __restrict__ b3,
    float* __restrict__ out)
{
  __shared__ _Float16 Hn[32 * 266];              // 17,024 B
  __shared__ _Float16 Xs[32 * 138];              //  8,832
  __shared__ _Float16 X2s[32 * 138];             //  8,832
  __shared__ alignas(16) _Float16 Bs[256 * 32];  // 16,384
  const int t = threadIdx.x;
  const int wave = t >> 6, lane = t & 63;
  const int quad = lane >> 4, lrow = lane & 15;
  const int rh = (wave >> 1) * 16;
  const int ch = wave & 1;
  const int r0 = blockIdx.x * 32;

  // ---- copy hn rows -> LDS ----
  {
    int row = t >> 3, seg = t & 7;
    int gr = r0 + row; if (gr > N_NODES - 1) gr = N_NODES - 1;
    const _Float16* g = hnh + (size_t)gr * 256 + seg * 32;
#pragma unroll
    for (int u = 0; u < 4; ++u)
      *(f16x8*)(Hn + row * 266 + seg * 32 + u * 8) = *(const f16x8*)(g + u * 8);
  }
  __syncthreads();

  // ---- x1 = relu(hn @ W1^T + b1): N=128, K=256 ----
  {
    f32x4 acc[4];
#pragma unroll
    for (int j = 0; j < 4; ++j) acc[j] = (f32x4)0.0f;
#pragma unroll
    for (int kc = 0; kc < 8; ++kc) {
      stage_tile<128, 4>(W1h, kc * 32, 256, Bs, wave, lane);
      f16x8 af = *(const f16x8*)(Hn + (rh + lrow) * 266 + kc * 32 + quad * 8);
      __syncthreads();
#pragma unroll
      for (int j = 0; j < 4; ++j) {
        f16x8 bf = read_B(Bs, ch * 64 + j * 16 + lrow, quad);
        acc[j] = __builtin_amdgcn_mfma_f32_16x16x32_f16(af, bf, acc[j], 0, 0, 0);
      }
      __syncthreads();
    }
#pragma unroll
    for (int j = 0; j < 4; ++j) {
      int col = ch * 64 + j * 16 + lrow;
      float bv = b1[col];
#pragma unroll
      for (int reg = 0; reg < 4; ++reg)
        Xs[(rh + quad * 4 + reg) * 138 + col] = (_Float16)fmaxf(acc[j][reg] + bv, 0.f);
    }
  }
  __syncthreads();

  // ---- x2 = relu(x1 @ W2^T + b2): N=128, K=128 ----
  {
    f32x4 acc[4];
#pragma unroll
    for (int j = 0; j < 4; ++j) acc[j] = (f32x4)0.0f;
#pragma unroll
    for (int kc = 0; kc < 4; ++kc) {
      stage_tile<128, 4>(W2h, kc * 32, 128, Bs, wave, lane);
      f16x8 af = *(const f16x8*)(Xs + (rh + lrow) * 138 + kc * 32 + quad * 8);
      __syncthreads();
#pragma unroll
      for (int j = 0; j < 4; ++j) {
        f16x8 bf = read_B(Bs, ch * 64 + j * 16 + lrow, quad);
        acc[j] = __builtin_amdgcn_mfma_f32_16x16x32_f16(af, bf, acc[j], 0, 0, 0);
      }
      __syncthreads();
    }
#pragma unroll
    for (int j = 0; j < 4; ++j) {
      int col = ch * 64 + j * 16 + lrow;
      float bv = b2[col];
#pragma unroll
      for (int reg = 0; reg < 4; ++reg)
        X2s[(rh + quad * 4 + reg) * 138 + col] = (_Float16)fmaxf(acc[j][reg] + bv, 0.f);
    }
  }
  __syncthreads();

  // ---- out = x2 @ W3^T + b3: N=256, K=128, fp32 out ----
  {
    f32x4 acc[8];
#pragma unroll
    for (int j = 0; j < 8; ++j) acc[j] = (f32x4)0.0f;
#pragma unroll
    for (int kc = 0; kc < 4; ++kc) {
      stage_tile<256, 4>(W3h, kc * 32, 128, Bs, wave, lane);
      f16x8 af = *(const f16x8*)(X2s + (rh + lrow) * 138 + kc * 32 + quad * 8);
      __syncthreads();
#pragma unroll
      for (int j = 0; j < 8; ++j) {
        f16x8 bf = read_B(Bs, ch * 128 + j * 16 + lrow, quad);
        acc[j] = __builtin_amdgcn_mfma_f32_16x16x32_f16(af, bf, acc[j], 0, 0, 0);
      }
      __syncthreads();
    }
#pragma unroll
    for (int j = 0; j < 8; ++j) {
      int col = ch * 128 + j * 16 + lrow;
      float bv = b3[col];
#pragma unroll
      for (int reg = 0; reg < 4; ++reg) {
        int gm = r0 + rh + quad * 4 + reg;
        if (gm < N_NODES) out[(size_t)gm * 256 + col] = acc[j][reg] + bv;
      }
    }
  }
}

// ---------- launch ----------
extern "C" void kernel_launch(void* const* d_in, const int* in_sizes, int n_in,
                              void* d_out, int out_size, void* d_ws, size_t ws_size,
                              hipStream_t stream) {
  const float* feat  = (const float*)d_in[0];
  const int* src = (const int*)d_in[1];
  const int* dst = (const int*)d_in[2];
  const int* rel = (const int*)d_in[3];
  const float* W_rel = (const float*)d_in[4];
  const float* b_rel = (const float*)d_in[5];
  const float* W_ih  = (const float*)d_in[6];
  const float* b_ih  = (const float*)d_in[7];
  const float* b_hh  = (const float*)d_in[8];
  const float* W1 = (const float*)d_in[9];
  const float* b1 = (const float*)d_in[10];
  const float* W2 = (const float*)d_in[11];
  const float* b2 = (const float*)d_in[12];
  const float* W3 = (const float*)d_in[13];
  const float* b3 = (const float*)d_in[14];
  float* out = (float*)d_out;

  char* ws = (char*)d_ws;
  _Float16* Mh   = (_Float16*)(ws);              // 10,240,000 B (2 rel slabs)
  _Float16* aggh = (_Float16*)(ws + 10240000);   //  5,120,000
  _Float16* hnh  = (_Float16*)(ws + 15360000);   //  5,120,000
  char* wsb = ws + 20480000;
  _Float16* W_relh = (_Float16*)(wsb);             // 262,144
  _Float16* Wg     = (_Float16*)(wsb + 262144);    // 393,216
  _Float16* W1h    = (_Float16*)(wsb + 655360);    // 65,536
  _Float16* W2h    = (_Float16*)(wsb + 720896);    // 32,768
  _Float16* W3h    = (_Float16*)(wsb + 753664);    // 65,536
  float*    bg     = (float*)(wsb + 819200);       // 3,072
  int*      cnt    = (int*)(wsb + 822272);         // 40,000
  int*      offs   = (int*)(wsb + 862272);         // 40,004 (+pad)
  int*      cursors= (int*)(wsb + 902280);         // 40,000
  unsigned int* rowoff = (unsigned int*)(wsb + 942280);  // 1,280,000

  (void)hipMemsetAsync(cnt, 0, N_NODES * sizeof(int), stream);
  prep_kernel<<<2853, 256, 0, stream>>>(W_rel, W_ih, b_ih, b_hh, W1, W2, W3,
                                        dst, cnt, W_relh, Wg, bg, W1h, W2h, W3h);
  scan_kernel<<<1, 1024, 0, stream>>>(cnt, offs, cursors, N_NODES);
  fill_kernel<<<1250, 256, 0, stream>>>(dst, src, rel, cursors, rowoff);

  // fused edge NN (both layers, both relations), 8 waves/block
  edge_fused<<<dim3(157, 2), 512, 0, stream>>>(feat, W_relh, b_rel, Mh);

  // scatter-sum via sorted gather
  agg_kernel<<<N_NODES, 256, 0, stream>>>(offs, rowoff, Mh, aggh);

  // gates GEMM with fused LSTM epilogue -> hn
  gates_lstm<<<dim3(8, 79), 256, 0, stream>>>(aggh, Wg, bg, hnh);

  // MLP -> out
  mlp_fused<<<313, 256, 0, stream>>>(hnh, W1h, b1, W2h, b2, W3h, b3, out);
}